// Round 1
// baseline (8237.825 us; speedup 1.0000x reference)
//
#include <hip/hip_runtime.h>
#include <cmath>

namespace {

constexpr int LT = 4;       // layers
constexpr int BB = 64;      // batch
constexpr int TT = 256;     // seq len
constexpr int DD = 512;     // model dim
constexpr int HH = 8;       // heads
constexpr int DH = 64;      // head dim
constexpr int FF = 2048;    // ffn inner
constexpr int CC = 25;      // tag classes
constexpr int M_ALL = BB * TT;   // 16384 token rows
constexpr int CHUNK = 4096;      // ffn row chunk (inner aliases q^T buffer)

__device__ __forceinline__ float wredsum(float v) {
#pragma unroll
  for (int o = 32; o > 0; o >>= 1) v += __shfl_xor(v, o, 64);
  return v;
}

// ---------------- embed (char|word|pos|spo concat) + LN0 ----------------
__global__ __launch_bounds__(64) void embed_ln0_k(
    const int* __restrict__ ch, const int* __restrict__ wd, const int* __restrict__ ps,
    const float* __restrict__ spo, const float* __restrict__ ctab,
    const float* __restrict__ wtab, const float* __restrict__ ptab,
    const float* __restrict__ g, const float* __restrict__ be, float* __restrict__ x) {
  const int row = blockIdx.x;
  const int lane = threadIdx.x;
  const int b = row >> 8;
  const int ci = ch[row], wi = wd[row], pi = ps[row];
  float v[8];
#pragma unroll
  for (int j = 0; j < 2; ++j) {
    const int d = j * 256 + lane * 4;
    float4 f;
    if (d < 128)      f = *(const float4*)&ctab[(size_t)ci * 128 + d];
    else if (d < 428) f = *(const float4*)&wtab[(size_t)wi * 300 + (d - 128)];
    else if (d < 492) f = *(const float4*)&ptab[(size_t)pi * 64 + (d - 428)];
    else              f = *(const float4*)&spo[(size_t)b * 20 + (d - 492)];
    v[j * 4 + 0] = f.x; v[j * 4 + 1] = f.y; v[j * 4 + 2] = f.z; v[j * 4 + 3] = f.w;
  }
  float s = 0.f;
#pragma unroll
  for (int i = 0; i < 8; ++i) s += v[i];
  const float mean = wredsum(s) * (1.0f / 512.0f);
  float vs = 0.f;
#pragma unroll
  for (int i = 0; i < 8; ++i) { const float d = v[i] - mean; vs += d * d; }
  const float rstd = rsqrtf(wredsum(vs) * (1.0f / 512.0f) + 1e-5f);
#pragma unroll
  for (int j = 0; j < 2; ++j) {
    const int d = j * 256 + lane * 4;
    const float4 gv = *(const float4*)&g[d];
    const float4 bv = *(const float4*)&be[d];
    float4 o;
    o.x = (v[j * 4 + 0] - mean) * rstd * gv.x + bv.x;
    o.y = (v[j * 4 + 1] - mean) * rstd * gv.y + bv.y;
    o.z = (v[j * 4 + 2] - mean) * rstd * gv.z + bv.z;
    o.w = (v[j * 4 + 3] - mean) * rstd * gv.w + bv.w;
    *(float4*)&x[(size_t)row * DD + d] = o;
  }
}

// ---------------- generic 64x64 tiled f32 GEMM, C = A[M,K] * B[K,N] + bias ----
// EPI: 0 bias, 1 bias+relu, 2 bias+residual, 3 bias+scatter q^T [B,H,DH,T],
//      4 bias+scatter [B,H,T,DH]
template <int EPI>
__global__ __launch_bounds__(256) void gemm64(const float* __restrict__ A,
                                              const float* __restrict__ Bw,
                                              const float* __restrict__ bias,
                                              const float* __restrict__ res,
                                              float* __restrict__ out,
                                              int M, int N, int K) {
  __shared__ float As[32][68];  // [kk][m]
  __shared__ float Bs[32][68];  // [kk][n]
  const int tid = threadIdx.x;
  const int tx = tid & 15, ty = tid >> 4;
  const int m0 = blockIdx.y * 64, n0 = blockIdx.x * 64;
  const int fa = tid & 7, ra = tid >> 3;    // A loader: 8 float4 per 32-k row
  const int cb = tid & 15, rb = tid >> 4;   // B loader
  float acc[4][4] = {};
  for (int k0 = 0; k0 < K; k0 += 32) {
    const float4 a0 = *(const float4*)&A[(size_t)(m0 + ra) * K + k0 + fa * 4];
    const float4 a1 = *(const float4*)&A[(size_t)(m0 + ra + 32) * K + k0 + fa * 4];
    const float4 b0 = *(const float4*)&Bw[(size_t)(k0 + rb) * N + n0 + cb * 4];
    const float4 b1 = *(const float4*)&Bw[(size_t)(k0 + rb + 16) * N + n0 + cb * 4];
    __syncthreads();
    As[fa * 4 + 0][ra] = a0.x; As[fa * 4 + 1][ra] = a0.y;
    As[fa * 4 + 2][ra] = a0.z; As[fa * 4 + 3][ra] = a0.w;
    As[fa * 4 + 0][ra + 32] = a1.x; As[fa * 4 + 1][ra + 32] = a1.y;
    As[fa * 4 + 2][ra + 32] = a1.z; As[fa * 4 + 3][ra + 32] = a1.w;
    *(float4*)&Bs[rb][cb * 4] = b0;
    *(float4*)&Bs[rb + 16][cb * 4] = b1;
    __syncthreads();
#pragma unroll
    for (int kk = 0; kk < 32; ++kk) {
      const float4 a4 = *(const float4*)&As[kk][ty * 4];
      const float4 b4 = *(const float4*)&Bs[kk][tx * 4];
      acc[0][0] += a4.x * b4.x; acc[0][1] += a4.x * b4.y;
      acc[0][2] += a4.x * b4.z; acc[0][3] += a4.x * b4.w;
      acc[1][0] += a4.y * b4.x; acc[1][1] += a4.y * b4.y;
      acc[1][2] += a4.y * b4.z; acc[1][3] += a4.y * b4.w;
      acc[2][0] += a4.z * b4.x; acc[2][1] += a4.z * b4.y;
      acc[2][2] += a4.z * b4.z; acc[2][3] += a4.z * b4.w;
      acc[3][0] += a4.w * b4.x; acc[3][1] += a4.w * b4.y;
      acc[3][2] += a4.w * b4.z; acc[3][3] += a4.w * b4.w;
    }
  }
  const float4 bv4 = *(const float4*)&bias[n0 + tx * 4];
  const float bvv[4] = {bv4.x, bv4.y, bv4.z, bv4.w};
#pragma unroll
  for (int i = 0; i < 4; ++i) {
    const int m = m0 + ty * 4 + i;
    float rr[4] = {0.f, 0.f, 0.f, 0.f};
    if constexpr (EPI == 2) {
      const float4 r4 = *(const float4*)&res[(size_t)m * N + n0 + tx * 4];
      rr[0] = r4.x; rr[1] = r4.y; rr[2] = r4.z; rr[3] = r4.w;
    }
    if constexpr (EPI == 3 || EPI == 4) {
#pragma unroll
      for (int j = 0; j < 4; ++j) {
        const float vv = acc[i][j] + bvv[j];
        const int n = n0 + tx * 4 + j;
        const int bb = m >> 8, t = m & 255, h = n >> 6, d = n & 63;
        if constexpr (EPI == 3)
          out[((size_t)((bb * HH + h) * DH + d) << 8) + t] = vv;   // [B,H,DH,T]
        else
          out[(size_t)((bb * HH + h) * TT + t) * DH + d] = vv;     // [B,H,T,DH]
      }
    } else {
      float4 o;
      o.x = acc[i][0] + bvv[0]; o.y = acc[i][1] + bvv[1];
      o.z = acc[i][2] + bvv[2]; o.w = acc[i][3] + bvv[3];
      if constexpr (EPI == 1) {
        o.x = fmaxf(o.x, 0.f); o.y = fmaxf(o.y, 0.f);
        o.z = fmaxf(o.z, 0.f); o.w = fmaxf(o.w, 0.f);
      }
      if constexpr (EPI == 2) { o.x += rr[0]; o.y += rr[1]; o.z += rr[2]; o.w += rr[3]; }
      *(float4*)&out[(size_t)m * N + n0 + tx * 4] = o;
    }
  }
}

// ---------------- single-pass flash attention, one lane per query ----------
// q^T: [B*H][DH][T], k/v: [B*H][T][DH], ctx out: [B][T][H*DH]
__global__ __launch_bounds__(256) void attn_k(const float* __restrict__ qt,
                                              const float* __restrict__ kb,
                                              const float* __restrict__ vb,
                                              const int* __restrict__ seq_len,
                                              float* __restrict__ ctx) {
  const int bh = blockIdx.x;
  const int b = bh >> 3, h = bh & 7;
  const int t = threadIdx.x;
  const int len = seq_len[b];
  const float* qp = qt + (size_t)bh * (DH * TT);
  const float* kp = kb + (size_t)bh * (TT * DH);
  const float* vp = vb + (size_t)bh * (TT * DH);
  float q[DH];
#pragma unroll
  for (int d = 0; d < DH; ++d) q[d] = qp[d * TT + t];  // coalesced
  float ctxr[DH];
#pragma unroll
  for (int d = 0; d < DH; ++d) ctxr[d] = 0.0f;
  float m = -3.0e38f, l = 0.0f;
  for (int kt = 0; kt < len; ++kt) {            // keys >= len are fully masked
    const float* kr = kp + kt * DH;             // wave-uniform -> scalar loads
    float s0 = 0.f, s1 = 0.f, s2 = 0.f, s3 = 0.f;
#pragma unroll
    for (int d = 0; d < DH; d += 4) {
      s0 += q[d + 0] * kr[d + 0];
      s1 += q[d + 1] * kr[d + 1];
      s2 += q[d + 2] * kr[d + 2];
      s3 += q[d + 3] * kr[d + 3];
    }
    const float s = ((s0 + s1) + (s2 + s3)) * 0.125f;   // / sqrt(64)
    if (s > m + 8.0f) {        // defer-max rescale (T13); exact softmax at the end
      const float sc = expf(m - s);
      m = s;
      l *= sc;
#pragma unroll
      for (int d = 0; d < DH; ++d) ctxr[d] *= sc;
    }
    const float p = expf(s - m);
    l += p;
    const float* vr = vp + kt * DH;
#pragma unroll
    for (int d = 0; d < DH; ++d) ctxr[d] += p * vr[d];
  }
  const float rl = 1.0f / l;  // len >= 1 always
  float* op = ctx + (size_t)(b * TT + t) * DD + h * DH;
#pragma unroll
  for (int d = 0; d < DH; d += 4) {
    float4 o;
    o.x = ctxr[d + 0] * rl; o.y = ctxr[d + 1] * rl;
    o.z = ctxr[d + 2] * rl; o.w = ctxr[d + 3] * rl;
    *(float4*)&op[d] = o;
  }
}

// ---------------- row LayerNorm; MODE 0: out=LN(a+b); MODE 1: out=LN(a)*mask -
template <int MODE>
__global__ __launch_bounds__(64) void ln_k(const float* __restrict__ a,
                                           const float* __restrict__ b2,
                                           const float* __restrict__ g,
                                           const float* __restrict__ be,
                                           const int* __restrict__ seq_len,
                                           float* __restrict__ out) {
  const int row = blockIdx.x, lane = threadIdx.x;
  float v[8];
#pragma unroll
  for (int j = 0; j < 2; ++j) {
    const int d = j * 256 + lane * 4;
    float4 f = *(const float4*)&a[(size_t)row * DD + d];
    if constexpr (MODE == 0) {
      const float4 f2 = *(const float4*)&b2[(size_t)row * DD + d];
      f.x += f2.x; f.y += f2.y; f.z += f2.z; f.w += f2.w;
    }
    v[j * 4 + 0] = f.x; v[j * 4 + 1] = f.y; v[j * 4 + 2] = f.z; v[j * 4 + 3] = f.w;
  }
  float s = 0.f;
#pragma unroll
  for (int i = 0; i < 8; ++i) s += v[i];
  const float mean = wredsum(s) * (1.0f / 512.0f);
  float vs = 0.f;
#pragma unroll
  for (int i = 0; i < 8; ++i) { const float d = v[i] - mean; vs += d * d; }
  const float rstd = rsqrtf(wredsum(vs) * (1.0f / 512.0f) + 1e-5f);
  float msk = 1.0f;
  if constexpr (MODE == 1) msk = ((row & 255) < seq_len[row >> 8]) ? 1.0f : 0.0f;
#pragma unroll
  for (int j = 0; j < 2; ++j) {
    const int d = j * 256 + lane * 4;
    const float4 gv = *(const float4*)&g[d];
    const float4 bv = *(const float4*)&be[d];
    float4 o;
    o.x = ((v[j * 4 + 0] - mean) * rstd * gv.x + bv.x) * msk;
    o.y = ((v[j * 4 + 1] - mean) * rstd * gv.y + bv.y) * msk;
    o.z = ((v[j * 4 + 2] - mean) * rstd * gv.z + bv.z) * msk;
    o.w = ((v[j * 4 + 3] - mean) * rstd * gv.w + bv.w) * msk;
    *(float4*)&out[(size_t)row * DD + d] = o;
  }
}

// ---------------- logits = x @ Wout + bout,  N=25 -------------------------
__global__ __launch_bounds__(256) void logits_k(const float* __restrict__ x,
                                                const float* __restrict__ W,
                                                const float* __restrict__ bo,
                                                float* __restrict__ lg) {
  __shared__ float xs[8][516];  // +4 pad: 8-row broadcast groups hit distinct banks
  const int r0 = blockIdx.x * 8;
  for (int i = threadIdx.x; i < 1024; i += 256) {
    const int rr = i >> 7, c4 = i & 127;
    *(float4*)&xs[rr][c4 * 4] = *(const float4*)&x[(size_t)(r0 + rr) * DD + c4 * 4];
  }
  __syncthreads();
  const int r = threadIdx.x >> 5, c = threadIdx.x & 31;
  if (c < CC) {
    float acc = 0.f;
#pragma unroll 8
    for (int k = 0; k < DD; ++k) acc += xs[r][k] * W[k * CC + c];
    lg[(size_t)(r0 + r) * CC + c] = acc + bo[c];
  }
}

// ---------------- CRF: forward scan (log_z) + gold score -------------------
__global__ __launch_bounds__(64) void crf_k(const float* __restrict__ lg,
                                            const int* __restrict__ tag,
                                            const int* __restrict__ seq_len,
                                            const float* __restrict__ trans,
                                            float* __restrict__ nll) {
  const int b = blockIdx.x;
  const int l = threadIdx.x;
  __shared__ float tr[CC * CC];
  __shared__ float al[2][CC];
  for (int i = l; i < CC * CC; i += 64) tr[i] = trans[i];
  if (l < CC) al[0][l] = lg[(size_t)(b * TT) * CC + l];
  __syncthreads();
  const int len = seq_len[b];
  float trc[CC];
  if (l < CC) {
#pragma unroll
    for (int i = 0; i < CC; ++i) trc[i] = tr[i * CC + l];  // column l of trans
  }
  int cur = 0;
  for (int t = 1; t < TT; ++t) {
    if (l < CC) {
      float mx = -3.0e38f;
#pragma unroll
      for (int i = 0; i < CC; ++i) mx = fmaxf(mx, al[cur][i] + trc[i]);
      float s = 0.f;
#pragma unroll
      for (int i = 0; i < CC; ++i) s += expf(al[cur][i] + trc[i] - mx);
      const float e = lg[(size_t)(b * TT + t) * CC + l];
      const float nv = mx + logf(s) + e;
      al[cur ^ 1][l] = (t < len) ? nv : al[cur][l];
    }
    __syncthreads();
    cur ^= 1;
  }
  float gold = 0.f;
  for (int t = l; t < TT; t += 64)
    if (t < len) gold += lg[(size_t)(b * TT + t) * CC + tag[b * TT + t]];
  for (int t = 1 + l; t < TT; t += 64)
    if (t < len) gold += tr[tag[b * TT + t - 1] * CC + tag[b * TT + t]];
  gold = wredsum(gold);
  if (l == 0) {
    float mx = -3.0e38f;
    for (int i = 0; i < CC; ++i) mx = fmaxf(mx, al[cur][i]);
    float s = 0.f;
    for (int i = 0; i < CC; ++i) s += expf(al[cur][i] - mx);
    nll[b] = (mx + logf(s)) - gold;
  }
}

__global__ __launch_bounds__(64) void final_k(const float* __restrict__ nll,
                                              float* __restrict__ out) {
  float v = nll[threadIdx.x];
  v = wredsum(v);
  if (threadIdx.x == 0) out[0] = v * (1.0f / 64.0f);
}

}  // namespace

extern "C" void kernel_launch(void* const* d_in, const int* in_sizes, int n_in,
                              void* d_out, int out_size, void* d_ws, size_t ws_size,
                              hipStream_t stream) {
  (void)in_sizes; (void)n_in; (void)out_size; (void)ws_size;
  const int* chi = (const int*)d_in[0];
  const int* wdi = (const int*)d_in[1];
  const int* psi = (const int*)d_in[2];
  const float* spo = (const float*)d_in[3];
  const int* seq_len = (const int*)d_in[4];
  const int* tag = (const int*)d_in[5];
  const float* ctab = (const float*)d_in[6];
  const float* wtab = (const float*)d_in[7];
  const float* ptab = (const float*)d_in[8];
  const float* ln0g = (const float*)d_in[9];
  const float* ln0b = (const float*)d_in[10];
  const float* Wq = (const float*)d_in[11];
  const float* bq = (const float*)d_in[12];
  const float* Wk = (const float*)d_in[13];
  const float* bk = (const float*)d_in[14];
  const float* Wv = (const float*)d_in[15];
  const float* bv = (const float*)d_in[16];
  const float* Wo = (const float*)d_in[17];
  const float* bo = (const float*)d_in[18];
  const float* ln1g = (const float*)d_in[19];
  const float* ln1b = (const float*)d_in[20];
  const float* W1 = (const float*)d_in[21];
  const float* b1 = (const float*)d_in[22];
  const float* W2 = (const float*)d_in[23];
  const float* b2 = (const float*)d_in[24];
  const float* ln2g = (const float*)d_in[25];
  const float* ln2b = (const float*)d_in[26];
  const float* Wout = (const float*)d_in[27];
  const float* bout = (const float*)d_in[28];
  const float* trans = (const float*)d_in[29];

  // workspace layout (floats), 8M-float (32MB) slabs; total ~194MB
  float* W = (float*)d_ws;
  const size_t SL = (size_t)8 * 1024 * 1024;
  float* x  = W;            // [16384][512] activations
  float* kb = W + SL;       // k [B,H,T,DH]
  float* vb = W + 2 * SL;   // v [B,H,T,DH]
  float* qt = W + 3 * SL;   // q^T [B,H,DH,T]; later aliased as FFN inner chunk
  float* t0 = W + 4 * SL;   // ctx / ffn-out
  float* h1 = W + 5 * SL;   // att_out -> h1
  float* lg = W + 6 * SL;   // logits [16384][25]
  float* nll = lg + (size_t)M_ALL * CC;

  embed_ln0_k<<<M_ALL, 64, 0, stream>>>(chi, wdi, psi, spo, ctab, wtab, ptab,
                                        ln0g, ln0b, x);

  const dim3 gsq(DD / 64, M_ALL / 64);
  for (int l = 0; l < LT; ++l) {
    const float* wq = Wq + (size_t)l * DD * DD;
    const float* wk = Wk + (size_t)l * DD * DD;
    const float* wv = Wv + (size_t)l * DD * DD;
    const float* wo = Wo + (size_t)l * DD * DD;
    gemm64<3><<<gsq, 256, 0, stream>>>(x, wq, bq + l * DD, nullptr, qt, M_ALL, DD, DD);
    gemm64<4><<<gsq, 256, 0, stream>>>(x, wk, bk + l * DD, nullptr, kb, M_ALL, DD, DD);
    gemm64<4><<<gsq, 256, 0, stream>>>(x, wv, bv + l * DD, nullptr, vb, M_ALL, DD, DD);
    attn_k<<<BB * HH, TT, 0, stream>>>(qt, kb, vb, seq_len, t0);
    gemm64<0><<<gsq, 256, 0, stream>>>(t0, wo, bo + l * DD, nullptr, h1, M_ALL, DD, DD);
    ln_k<0><<<M_ALL, 64, 0, stream>>>(h1, x, ln1g + l * DD, ln1b + l * DD, nullptr, h1);
    for (int c = 0; c < M_ALL / CHUNK; ++c) {
      const float* hc = h1 + (size_t)c * CHUNK * DD;
      gemm64<1><<<dim3(FF / 64, CHUNK / 64), 256, 0, stream>>>(
          hc, W1 + (size_t)l * DD * FF, b1 + l * FF, nullptr, qt, CHUNK, FF, DD);
      gemm64<2><<<dim3(DD / 64, CHUNK / 64), 256, 0, stream>>>(
          qt, W2 + (size_t)l * FF * DD, b2 + l * DD, hc,
          t0 + (size_t)c * CHUNK * DD, CHUNK, DD, FF);
    }
    ln_k<1><<<M_ALL, 64, 0, stream>>>(t0, nullptr, ln2g + l * DD, ln2b + l * DD,
                                      seq_len, x);
  }
  logits_k<<<M_ALL / 8, 256, 0, stream>>>(x, Wout, bout, lg);
  crf_k<<<BB, 64, 0, stream>>>(lg, tag, seq_len, trans, nll);
  final_k<<<1, 64, 0, stream>>>(nll, (float*)d_out);
}

// Round 2
// 1986.314 us; speedup vs baseline: 4.1473x; 4.1473x over previous
//
#include <hip/hip_runtime.h>
#include <cmath>

namespace {

constexpr int LT = 4;       // layers
constexpr int BB = 64;      // batch
constexpr int TT = 256;     // seq len
constexpr int DD = 512;     // model dim
constexpr int HH = 8;       // heads
constexpr int DH = 64;      // head dim
constexpr int FF = 2048;    // ffn inner
constexpr int CC = 25;      // tag classes
constexpr int M_ALL = BB * TT;   // 16384 token rows
constexpr size_t MB = 1024 * 1024;

typedef __attribute__((ext_vector_type(8))) short short8;
typedef __attribute__((ext_vector_type(4))) short short4_;
typedef __attribute__((ext_vector_type(4))) float f32x4;

__device__ __forceinline__ float b2f(unsigned short u) {
  union { unsigned int i; float f; } x; x.i = ((unsigned int)u) << 16; return x.f;
}
__device__ __forceinline__ unsigned short f2b(float f) {
  union { float f; unsigned int i; } x; x.f = f;
  unsigned int r = x.i + 0x7FFFu + ((x.i >> 16) & 1u);
  return (unsigned short)(r >> 16);
}
__device__ __forceinline__ void gl_lds16(const void* g, void* l) {
  __builtin_amdgcn_global_load_lds(
      (const __attribute__((address_space(1))) unsigned int*)g,
      (__attribute__((address_space(3))) unsigned int*)l, 16, 0, 0);
}
__device__ __forceinline__ float wredsum(float v) {
#pragma unroll
  for (int o = 32; o > 0; o >>= 1) v += __shfl_xor(v, o, 64);
  return v;
}

// ---------------- weight convert+transpose: in [K,N] f32 -> out [N,K] bf16 ---
__global__ __launch_bounds__(256) void wconv_k(const float* __restrict__ in,
                                               unsigned short* __restrict__ out,
                                               int K, int N) {
  __shared__ float ts[64][65];
  const int k0 = blockIdx.x * 64, n0 = blockIdx.y * 64;
  in += (size_t)blockIdx.z * K * N;
  out += (size_t)blockIdx.z * K * N;
  const int tid = threadIdx.x;
  for (int i = tid; i < 1024; i += 256) {
    const int r = i >> 4, c4 = i & 15;
    const float4 f = *(const float4*)&in[(size_t)(k0 + r) * N + n0 + c4 * 4];
    ts[r][c4 * 4 + 0] = f.x; ts[r][c4 * 4 + 1] = f.y;
    ts[r][c4 * 4 + 2] = f.z; ts[r][c4 * 4 + 3] = f.w;
  }
  __syncthreads();
  const int n_r = tid >> 2, kc = (tid & 3) * 16;
  short8 v0, v1;
#pragma unroll
  for (int j = 0; j < 8; ++j) {
    v0[j] = (short)f2b(ts[kc + j][n_r]);
    v1[j] = (short)f2b(ts[kc + 8 + j][n_r]);
  }
  unsigned short* op = out + (size_t)(n0 + n_r) * K + k0 + kc;
  *(short8*)op = v0;
  *(short8*)(op + 8) = v1;
}

// ---------------- embed (char|word|pos|spo concat) + LN0, dual f32/bf16 out --
__global__ __launch_bounds__(64) void embed_ln0_k(
    const int* __restrict__ ch, const int* __restrict__ wd, const int* __restrict__ ps,
    const float* __restrict__ spo, const float* __restrict__ ctab,
    const float* __restrict__ wtab, const float* __restrict__ ptab,
    const float* __restrict__ g, const float* __restrict__ be,
    float* __restrict__ x, unsigned short* __restrict__ xb) {
  const int row = blockIdx.x;
  const int lane = threadIdx.x;
  const int b = row >> 8;
  const int ci = ch[row], wi = wd[row], pi = ps[row];
  float v[8];
#pragma unroll
  for (int j = 0; j < 2; ++j) {
    const int d = j * 256 + lane * 4;
    float4 f;
    if (d < 128)      f = *(const float4*)&ctab[(size_t)ci * 128 + d];
    else if (d < 428) f = *(const float4*)&wtab[(size_t)wi * 300 + (d - 128)];
    else if (d < 492) f = *(const float4*)&ptab[(size_t)pi * 64 + (d - 428)];
    else              f = *(const float4*)&spo[(size_t)b * 20 + (d - 492)];
    v[j * 4 + 0] = f.x; v[j * 4 + 1] = f.y; v[j * 4 + 2] = f.z; v[j * 4 + 3] = f.w;
  }
  float s = 0.f;
#pragma unroll
  for (int i = 0; i < 8; ++i) s += v[i];
  const float mean = wredsum(s) * (1.0f / 512.0f);
  float vs = 0.f;
#pragma unroll
  for (int i = 0; i < 8; ++i) { const float d = v[i] - mean; vs += d * d; }
  const float rstd = rsqrtf(wredsum(vs) * (1.0f / 512.0f) + 1e-5f);
#pragma unroll
  for (int j = 0; j < 2; ++j) {
    const int d = j * 256 + lane * 4;
    const float4 gv = *(const float4*)&g[d];
    const float4 bv = *(const float4*)&be[d];
    float4 o;
    o.x = (v[j * 4 + 0] - mean) * rstd * gv.x + bv.x;
    o.y = (v[j * 4 + 1] - mean) * rstd * gv.y + bv.y;
    o.z = (v[j * 4 + 2] - mean) * rstd * gv.z + bv.z;
    o.w = (v[j * 4 + 3] - mean) * rstd * gv.w + bv.w;
    *(float4*)&x[(size_t)row * DD + d] = o;
    short4_ ob;
    ob[0] = (short)f2b(o.x); ob[1] = (short)f2b(o.y);
    ob[2] = (short)f2b(o.z); ob[3] = (short)f2b(o.w);
    *(short4_*)&xb[(size_t)row * DD + d] = ob;
  }
}

// ---------------- MFMA GEMM: C = A[M,K](bf16) * Bt[N,K](bf16)^T + bias -------
// 128x128 tile, BK=64, 4 waves, each wave 64x64 via 4x4 16x16x32 frags.
// EPI: 0 f32 out+bias; 1 bf16 out+bias+relu; 2 f32 out+bias+residual;
//      3 bf16 scatter q^T [B,H,DH,T]+bias; 4 bf16 scatter [B,H,T,DH]+bias
template <int EPI>
__global__ __launch_bounds__(256) void gemm_mfma(
    const unsigned short* __restrict__ A, const unsigned short* __restrict__ Bt,
    const float* __restrict__ bias, const float* __restrict__ res,
    void* __restrict__ outv, int M, int N, int K) {
  __shared__ unsigned short As[128 * 64];  // [m][k] with XOR-swizzled k-bytes
  __shared__ unsigned short Bs[128 * 64];  // [n][k] same
  const int tid = threadIdx.x;
  const int m0 = blockIdx.y * 128, n0 = blockIdx.x * 128;
  const int wid = tid >> 6, lane = tid & 63;
  const int wr = wid >> 1, wc = wid & 1;
  const int cl = lane & 15, rg = lane >> 4;
  f32x4 acc[4][4];
#pragma unroll
  for (int i = 0; i < 4; ++i)
#pragma unroll
    for (int j = 0; j < 4; ++j) acc[i][j] = (f32x4){0.f, 0.f, 0.f, 0.f};

  const int rbase = tid >> 3, sl = tid & 7;
  const int sc = 8 * (sl ^ (rbase & 7));  // pre-swizzled source column (elems)

  for (int k0 = 0; k0 < K; k0 += 64) {
    if (k0) __syncthreads();
#pragma unroll
    for (int i = 0; i < 4; ++i) {
      const int r = i * 32 + rbase;
      gl_lds16(A + (size_t)(m0 + r) * K + k0 + sc, (char*)As + (i * 256 + tid) * 16);
      gl_lds16(Bt + (size_t)(n0 + r) * K + k0 + sc, (char*)Bs + (i * 256 + tid) * 16);
    }
    __syncthreads();  // drains vmcnt(0): staged data visible
#pragma unroll
    for (int ks = 0; ks < 2; ++ks) {
      short8 a[4], b[4];
      const int kbyte = ks * 64 + rg * 16;
#pragma unroll
      for (int f = 0; f < 4; ++f) {
        const int am = wr * 64 + f * 16 + cl;
        a[f] = *(const short8*)((const char*)As + am * 128 + (kbyte ^ ((am & 7) << 4)));
        const int bn = wc * 64 + f * 16 + cl;
        b[f] = *(const short8*)((const char*)Bs + bn * 128 + (kbyte ^ ((bn & 7) << 4)));
      }
#pragma unroll
      for (int mi = 0; mi < 4; ++mi)
#pragma unroll
        for (int ni = 0; ni < 4; ++ni)
          acc[mi][ni] = __builtin_amdgcn_mfma_f32_16x16x32_bf16(a[mi], b[ni],
                                                                acc[mi][ni], 0, 0, 0);
    }
  }

#pragma unroll
  for (int ni = 0; ni < 4; ++ni) {
    const int n = n0 + wc * 64 + ni * 16 + cl;
    const float bv = bias[n];
#pragma unroll
    for (int mi = 0; mi < 4; ++mi) {
#pragma unroll
      for (int i = 0; i < 4; ++i) {
        const int m = m0 + wr * 64 + mi * 16 + rg * 4 + i;
        float v = acc[mi][ni][i] + bv;
        if constexpr (EPI == 0) {
          ((float*)outv)[(size_t)m * N + n] = v;
        } else if constexpr (EPI == 1) {
          ((unsigned short*)outv)[(size_t)m * N + n] = f2b(fmaxf(v, 0.f));
        } else if constexpr (EPI == 2) {
          ((float*)outv)[(size_t)m * N + n] = v + res[(size_t)m * N + n];
        } else {
          const int bb = m >> 8, t = m & 255, hh = n >> 6, d = n & 63;
          if constexpr (EPI == 3)
            ((unsigned short*)outv)[(((size_t)(bb * HH + hh) * DH + d) << 8) + t] = f2b(v);
          else
            ((unsigned short*)outv)[(((size_t)(bb * HH + hh) * TT + t) << 6) + d] = f2b(v);
        }
      }
    }
  }
}

// ---------------- flash attention, one lane per query, LDS-tiled K/V --------
// qt [B,H,DH,T] bf16, kb/vb [B,H,T,DH] bf16, ctx out cb [B,T,H*DH] bf16
__global__ __launch_bounds__(256) void attn_k(const unsigned short* __restrict__ qt,
                                              const unsigned short* __restrict__ kb,
                                              const unsigned short* __restrict__ vb,
                                              const int* __restrict__ seq_len,
                                              unsigned short* __restrict__ cb) {
  __shared__ float Kf[64][68];  // +4 pad: staged-write lanes spread over banks
  __shared__ float Vf[64][68];
  const int bh = blockIdx.x;
  const int b = bh >> 3, h = bh & 7;
  const int t = threadIdx.x;
  const int len = seq_len[b];
  float q[DH];
  {
    const unsigned short* qp = qt + (size_t)bh * (DH * TT) + t;
#pragma unroll
    for (int d = 0; d < DH; ++d) q[d] = b2f(qp[d * TT]);  // coalesced across lanes
  }
  float ctx[DH];
#pragma unroll
  for (int d = 0; d < DH; ++d) ctx[d] = 0.f;
  float m = -3.0e38f, l = 0.f;
  const int skey = threadIdx.x >> 2, sd = (threadIdx.x & 3) * 16;
  for (int kt0 = 0; kt0 < len; kt0 += 64) {
    __syncthreads();
    {  // stage 64 keys of K and V, bf16 -> f32
      const unsigned short* kr = kb + ((size_t)bh * TT + kt0 + skey) * DH + sd;
      const unsigned short* vr = vb + ((size_t)bh * TT + kt0 + skey) * DH + sd;
      short8 ka = *(const short8*)kr, kc2 = *(const short8*)(kr + 8);
      short8 va = *(const short8*)vr, vc2 = *(const short8*)(vr + 8);
#pragma unroll
      for (int j = 0; j < 8; ++j) {
        Kf[skey][sd + j] = b2f((unsigned short)ka[j]);
        Kf[skey][sd + 8 + j] = b2f((unsigned short)kc2[j]);
        Vf[skey][sd + j] = b2f((unsigned short)va[j]);
        Vf[skey][sd + 8 + j] = b2f((unsigned short)vc2[j]);
      }
    }
    __syncthreads();
    const int kend = min(64, len - kt0);
    for (int kk = 0; kk < kend; ++kk) {
      const float* krow = &Kf[kk][0];
      float s0 = 0.f, s1 = 0.f, s2 = 0.f, s3 = 0.f;
#pragma unroll
      for (int d = 0; d < DH; d += 4) {
        const float4 kv = *(const float4*)&krow[d];  // broadcast, conflict-free
        s0 += q[d + 0] * kv.x; s1 += q[d + 1] * kv.y;
        s2 += q[d + 2] * kv.z; s3 += q[d + 3] * kv.w;
      }
      const float s = ((s0 + s1) + (s2 + s3)) * 0.125f;
      if (s > m + 8.0f) {  // defer-max rescale (T13)
        const float scl = __expf(m - s);
        m = s; l *= scl;
#pragma unroll
        for (int d = 0; d < DH; ++d) ctx[d] *= scl;
      }
      const float p = __expf(s - m);
      l += p;
      const float* vrow = &Vf[kk][0];
#pragma unroll
      for (int d = 0; d < DH; d += 4) {
        const float4 vv = *(const float4*)&vrow[d];
        ctx[d + 0] += p * vv.x; ctx[d + 1] += p * vv.y;
        ctx[d + 2] += p * vv.z; ctx[d + 3] += p * vv.w;
      }
    }
  }
  const float rl = 1.0f / l;  // len >= 1 always
  unsigned short* op = cb + ((size_t)(b * TT + t)) * DD + h * DH;
#pragma unroll
  for (int d = 0; d < DH; d += 8) {
    short8 o;
#pragma unroll
    for (int j = 0; j < 8; ++j) o[j] = (short)f2b(ctx[d + j] * rl);
    *(short8*)&op[d] = o;
  }
}

// ---------------- row LayerNorm, dual f32/bf16 out --------------------------
// MODE 0: out=LN(a+b2); MODE 1: out=LN(a)*mask
template <int MODE>
__global__ __launch_bounds__(64) void ln_k(const float* __restrict__ a,
                                           const float* __restrict__ b2,
                                           const float* __restrict__ g,
                                           const float* __restrict__ be,
                                           const int* __restrict__ seq_len,
                                           float* __restrict__ out,
                                           unsigned short* __restrict__ outb) {
  const int row = blockIdx.x, lane = threadIdx.x;
  float v[8];
#pragma unroll
  for (int j = 0; j < 2; ++j) {
    const int d = j * 256 + lane * 4;
    float4 f = *(const float4*)&a[(size_t)row * DD + d];
    if constexpr (MODE == 0) {
      const float4 f2 = *(const float4*)&b2[(size_t)row * DD + d];
      f.x += f2.x; f.y += f2.y; f.z += f2.z; f.w += f2.w;
    }
    v[j * 4 + 0] = f.x; v[j * 4 + 1] = f.y; v[j * 4 + 2] = f.z; v[j * 4 + 3] = f.w;
  }
  float s = 0.f;
#pragma unroll
  for (int i = 0; i < 8; ++i) s += v[i];
  const float mean = wredsum(s) * (1.0f / 512.0f);
  float vs = 0.f;
#pragma unroll
  for (int i = 0; i < 8; ++i) { const float d = v[i] - mean; vs += d * d; }
  const float rstd = rsqrtf(wredsum(vs) * (1.0f / 512.0f) + 1e-5f);
  float msk = 1.0f;
  if constexpr (MODE == 1) msk = ((row & 255) < seq_len[row >> 8]) ? 1.0f : 0.0f;
#pragma unroll
  for (int j = 0; j < 2; ++j) {
    const int d = j * 256 + lane * 4;
    const float4 gv = *(const float4*)&g[d];
    const float4 bv = *(const float4*)&be[d];
    float4 o;
    o.x = ((v[j * 4 + 0] - mean) * rstd * gv.x + bv.x) * msk;
    o.y = ((v[j * 4 + 1] - mean) * rstd * gv.y + bv.y) * msk;
    o.z = ((v[j * 4 + 2] - mean) * rstd * gv.z + bv.z) * msk;
    o.w = ((v[j * 4 + 3] - mean) * rstd * gv.w + bv.w) * msk;
    *(float4*)&out[(size_t)row * DD + d] = o;
    short4_ ob;
    ob[0] = (short)f2b(o.x); ob[1] = (short)f2b(o.y);
    ob[2] = (short)f2b(o.z); ob[3] = (short)f2b(o.w);
    *(short4_*)&outb[(size_t)row * DD + d] = ob;
  }
}

// ---------------- logits = x @ Wout + bout,  N=25 ---------------------------
__global__ __launch_bounds__(256) void logits_k(const float* __restrict__ x,
                                                const float* __restrict__ W,
                                                const float* __restrict__ bo,
                                                float* __restrict__ lg) {
  __shared__ float xs[8][516];
  const int r0 = blockIdx.x * 8;
  for (int i = threadIdx.x; i < 1024; i += 256) {
    const int rr = i >> 7, c4 = i & 127;
    *(float4*)&xs[rr][c4 * 4] = *(const float4*)&x[(size_t)(r0 + rr) * DD + c4 * 4];
  }
  __syncthreads();
  const int r = threadIdx.x >> 5, c = threadIdx.x & 31;
  if (c < CC) {
    float acc = 0.f;
#pragma unroll 8
    for (int k = 0; k < DD; ++k) acc += xs[r][k] * W[k * CC + c];
    lg[(size_t)(r0 + r) * CC + c] = acc + bo[c];
  }
}

// ---------------- CRF: forward scan (log_z) + gold score --------------------
__global__ __launch_bounds__(64) void crf_k(const float* __restrict__ lg,
                                            const int* __restrict__ tag,
                                            const int* __restrict__ seq_len,
                                            const float* __restrict__ trans,
                                            float* __restrict__ nll) {
  const int b = blockIdx.x;
  const int l = threadIdx.x;
  __shared__ float tr[CC * CC];
  __shared__ float al[2][CC];
  for (int i = l; i < CC * CC; i += 64) tr[i] = trans[i];
  if (l < CC) al[0][l] = lg[(size_t)(b * TT) * CC + l];
  __syncthreads();
  const int len = seq_len[b];
  float trc[CC];
  if (l < CC) {
#pragma unroll
    for (int i = 0; i < CC; ++i) trc[i] = tr[i * CC + l];
  }
  int cur = 0;
  for (int t = 1; t < TT; ++t) {
    if (l < CC) {
      float mx = -3.0e38f;
#pragma unroll
      for (int i = 0; i < CC; ++i) mx = fmaxf(mx, al[cur][i] + trc[i]);
      float s = 0.f;
#pragma unroll
      for (int i = 0; i < CC; ++i) s += expf(al[cur][i] + trc[i] - mx);
      const float e = lg[(size_t)(b * TT + t) * CC + l];
      const float nv = mx + logf(s) + e;
      al[cur ^ 1][l] = (t < len) ? nv : al[cur][l];
    }
    __syncthreads();
    cur ^= 1;
  }
  float gold = 0.f;
  for (int t = l; t < TT; t += 64)
    if (t < len) gold += lg[(size_t)(b * TT + t) * CC + tag[b * TT + t]];
  for (int t = 1 + l; t < TT; t += 64)
    if (t < len) gold += tr[tag[b * TT + t - 1] * CC + tag[b * TT + t]];
  gold = wredsum(gold);
  if (l == 0) {
    float mx = -3.0e38f;
    for (int i = 0; i < CC; ++i) mx = fmaxf(mx, al[cur][i]);
    float s = 0.f;
    for (int i = 0; i < CC; ++i) s += expf(al[cur][i] - mx);
    nll[b] = (mx + logf(s)) - gold;
  }
}

__global__ __launch_bounds__(64) void final_k(const float* __restrict__ nll,
                                              float* __restrict__ out) {
  float v = nll[threadIdx.x];
  v = wredsum(v);
  if (threadIdx.x == 0) out[0] = v * (1.0f / 64.0f);
}

}  // namespace

extern "C" void kernel_launch(void* const* d_in, const int* in_sizes, int n_in,
                              void* d_out, int out_size, void* d_ws, size_t ws_size,
                              hipStream_t stream) {
  (void)in_sizes; (void)n_in; (void)out_size; (void)ws_size;
  const int* chi = (const int*)d_in[0];
  const int* wdi = (const int*)d_in[1];
  const int* psi = (const int*)d_in[2];
  const float* spo = (const float*)d_in[3];
  const int* seq_len = (const int*)d_in[4];
  const int* tag = (const int*)d_in[5];
  const float* ctab = (const float*)d_in[6];
  const float* wtab = (const float*)d_in[7];
  const float* ptab = (const float*)d_in[8];
  const float* ln0g = (const float*)d_in[9];
  const float* ln0b = (const float*)d_in[10];
  const float* Wq = (const float*)d_in[11];
  const float* bq = (const float*)d_in[12];
  const float* Wk = (const float*)d_in[13];
  const float* bk = (const float*)d_in[14];
  const float* Wv = (const float*)d_in[15];
  const float* bv = (const float*)d_in[16];
  const float* Wo = (const float*)d_in[17];
  const float* bo = (const float*)d_in[18];
  const float* ln1g = (const float*)d_in[19];
  const float* ln1b = (const float*)d_in[20];
  const float* W1 = (const float*)d_in[21];
  const float* b1 = (const float*)d_in[22];
  const float* W2 = (const float*)d_in[23];
  const float* b2 = (const float*)d_in[24];
  const float* ln2g = (const float*)d_in[25];
  const float* ln2b = (const float*)d_in[26];
  const float* Wout = (const float*)d_in[27];
  const float* bout = (const float*)d_in[28];
  const float* trans = (const float*)d_in[29];

  // ---- workspace layout (~186 MB) ----
  char* w8 = (char*)d_ws;
  float* x = (float*)(w8);                              // 32MB f32 activations
  float* t0 = (float*)(w8 + 32 * MB);                   // 32MB ffn-out f32
  unsigned short* cb = (unsigned short*)t0;             // ctx bf16 (dead before t0 write)
  float* h1f = (float*)(w8 + 64 * MB);                  // 32MB h1 f32
  unsigned short* xb = (unsigned short*)(w8 + 96 * MB); // 16MB x bf16
  unsigned short* qt = (unsigned short*)(w8 + 112 * MB);// 16MB q^T bf16 [B,H,DH,T]
  unsigned short* ib = qt;                              // 32MB ffn inner bf16 (qt+kb, post-attn)
  unsigned short* kb = (unsigned short*)(w8 + 128 * MB);// 16MB k bf16 [B,H,T,DH]
  unsigned short* vb = (unsigned short*)(w8 + 144 * MB);// 16MB v bf16
  unsigned short* hb = vb;                              // h1 bf16 (vb dead post-attn)
  unsigned short* wqt = (unsigned short*)(w8 + 160 * MB);
  unsigned short* wkt = (unsigned short*)(w8 + 162 * MB);
  unsigned short* wvt = (unsigned short*)(w8 + 164 * MB);
  unsigned short* wot = (unsigned short*)(w8 + 166 * MB);
  unsigned short* w1t = (unsigned short*)(w8 + 168 * MB);  // [L][2048][512]
  unsigned short* w2t = (unsigned short*)(w8 + 176 * MB);  // [L][512][2048]
  float* lg = (float*)(w8 + 184 * MB);
  float* nll = (float*)(w8 + 186 * MB);

  // weight f32 [K,N] -> bf16 [N,K] (per launch; deterministic)
  wconv_k<<<dim3(8, 8, LT), 256, 0, stream>>>(Wq, wqt, DD, DD);
  wconv_k<<<dim3(8, 8, LT), 256, 0, stream>>>(Wk, wkt, DD, DD);
  wconv_k<<<dim3(8, 8, LT), 256, 0, stream>>>(Wv, wvt, DD, DD);
  wconv_k<<<dim3(8, 8, LT), 256, 0, stream>>>(Wo, wot, DD, DD);
  wconv_k<<<dim3(8, 32, LT), 256, 0, stream>>>(W1, w1t, DD, FF);
  wconv_k<<<dim3(32, 8, LT), 256, 0, stream>>>(W2, w2t, FF, DD);

  embed_ln0_k<<<M_ALL, 64, 0, stream>>>(chi, wdi, psi, spo, ctab, wtab, ptab,
                                        ln0g, ln0b, x, xb);

  const dim3 gqkv(DD / 128, M_ALL / 128);  // 4 x 128
  for (int l = 0; l < LT; ++l) {
    gemm_mfma<3><<<gqkv, 256, 0, stream>>>(xb, wqt + (size_t)l * DD * DD,
                                           bq + l * DD, nullptr, qt, M_ALL, DD, DD);
    gemm_mfma<4><<<gqkv, 256, 0, stream>>>(xb, wkt + (size_t)l * DD * DD,
                                           bk + l * DD, nullptr, kb, M_ALL, DD, DD);
    gemm_mfma<4><<<gqkv, 256, 0, stream>>>(xb, wvt + (size_t)l * DD * DD,
                                           bv + l * DD, nullptr, vb, M_ALL, DD, DD);
    attn_k<<<BB * HH, TT, 0, stream>>>(qt, kb, vb, seq_len, cb);
    gemm_mfma<0><<<gqkv, 256, 0, stream>>>(cb, wot + (size_t)l * DD * DD,
                                           bo + l * DD, nullptr, h1f, M_ALL, DD, DD);
    ln_k<0><<<M_ALL, 64, 0, stream>>>(h1f, x, ln1g + l * DD, ln1b + l * DD,
                                      nullptr, h1f, hb);
    for (int c = 0; c < 2; ++c) {  // 2 x 8192-row chunks (inner aliases qt+kb)
      const size_t ro = (size_t)c * 8192 * DD;
      gemm_mfma<1><<<dim3(FF / 128, 8192 / 128), 256, 0, stream>>>(
          hb + ro, w1t + (size_t)l * FF * DD, b1 + l * FF, nullptr, ib, 8192, FF, DD);
      gemm_mfma<2><<<dim3(DD / 128, 8192 / 128), 256, 0, stream>>>(
          ib, w2t + (size_t)l * FF * DD, b2 + l * DD, h1f + ro, t0 + ro, 8192, DD, FF);
    }
    ln_k<1><<<M_ALL, 64, 0, stream>>>(t0, nullptr, ln2g + l * DD, ln2b + l * DD,
                                      seq_len, x, xb);
  }
  logits_k<<<M_ALL / 8, 256, 0, stream>>>(x, Wout, bout, lg);
  crf_k<<<BB, 64, 0, stream>>>(lg, tag, seq_len, trans, nll);
  final_k<<<1, 64, 0, stream>>>(nll, (float*)d_out);
}

// Round 3
// 1810.049 us; speedup vs baseline: 4.5512x; 1.0974x over previous
//
#include <hip/hip_runtime.h>
#include <cmath>

namespace {

constexpr int LT = 4;       // layers
constexpr int BB = 64;      // batch
constexpr int TT = 256;     // seq len
constexpr int DD = 512;     // model dim
constexpr int HH = 8;       // heads
constexpr int DH = 64;      // head dim
constexpr int FF = 2048;    // ffn inner
constexpr int CC = 25;      // tag classes
constexpr int M_ALL = BB * TT;   // 16384 token rows
constexpr size_t MB = 1024 * 1024;

typedef __attribute__((ext_vector_type(8))) short short8;
typedef __attribute__((ext_vector_type(4))) short short4_;
typedef __attribute__((ext_vector_type(4))) float f32x4;

__device__ __forceinline__ float b2f(unsigned short u) {
  union { unsigned int i; float f; } x; x.i = ((unsigned int)u) << 16; return x.f;
}
__device__ __forceinline__ unsigned short f2b(float f) {
  union { float f; unsigned int i; } x; x.f = f;
  unsigned int r = x.i + 0x7FFFu + ((x.i >> 16) & 1u);
  return (unsigned short)(r >> 16);
}
__device__ __forceinline__ void gl_lds16(const void* g, void* l) {
  __builtin_amdgcn_global_load_lds(
      (const __attribute__((address_space(1))) unsigned int*)g,
      (__attribute__((address_space(3))) unsigned int*)l, 16, 0, 0);
}
__device__ __forceinline__ float wredsum(float v) {
#pragma unroll
  for (int o = 32; o > 0; o >>= 1) v += __shfl_xor(v, o, 64);
  return v;
}

// ---------------- weight convert+transpose: in [K,N] f32 -> out [N,K] bf16 ---
// lstride = per-layer element stride of out (for packing into fused slabs)
__global__ __launch_bounds__(256) void wconv_k(const float* __restrict__ in,
                                               unsigned short* __restrict__ out,
                                               int K, int N, size_t lstride) {
  __shared__ float ts[64][65];
  const int k0 = blockIdx.x * 64, n0 = blockIdx.y * 64;
  in += (size_t)blockIdx.z * K * N;
  out += (size_t)blockIdx.z * lstride;
  const int tid = threadIdx.x;
  for (int i = tid; i < 1024; i += 256) {
    const int r = i >> 4, c4 = i & 15;
    const float4 f = *(const float4*)&in[(size_t)(k0 + r) * N + n0 + c4 * 4];
    ts[r][c4 * 4 + 0] = f.x; ts[r][c4 * 4 + 1] = f.y;
    ts[r][c4 * 4 + 2] = f.z; ts[r][c4 * 4 + 3] = f.w;
  }
  __syncthreads();
  const int n_r = tid >> 2, kc = (tid & 3) * 16;
  short8 v0, v1;
#pragma unroll
  for (int j = 0; j < 8; ++j) {
    v0[j] = (short)f2b(ts[kc + j][n_r]);
    v1[j] = (short)f2b(ts[kc + 8 + j][n_r]);
  }
  unsigned short* op = out + (size_t)(n0 + n_r) * K + k0 + kc;
  *(short8*)op = v0;
  *(short8*)(op + 8) = v1;
}

// ---------------- embed (char|word|pos|spo concat) + LN0, dual f32/bf16 out --
__global__ __launch_bounds__(64) void embed_ln0_k(
    const int* __restrict__ ch, const int* __restrict__ wd, const int* __restrict__ ps,
    const float* __restrict__ spo, const float* __restrict__ ctab,
    const float* __restrict__ wtab, const float* __restrict__ ptab,
    const float* __restrict__ g, const float* __restrict__ be,
    float* __restrict__ x, unsigned short* __restrict__ xb) {
  const int row = blockIdx.x;
  const int lane = threadIdx.x;
  const int b = row >> 8;
  const int ci = ch[row], wi = wd[row], pi = ps[row];
  float v[8];
#pragma unroll
  for (int j = 0; j < 2; ++j) {
    const int d = j * 256 + lane * 4;
    float4 f;
    if (d < 128)      f = *(const float4*)&ctab[(size_t)ci * 128 + d];
    else if (d < 428) f = *(const float4*)&wtab[(size_t)wi * 300 + (d - 128)];
    else if (d < 492) f = *(const float4*)&ptab[(size_t)pi * 64 + (d - 428)];
    else              f = *(const float4*)&spo[(size_t)b * 20 + (d - 492)];
    v[j * 4 + 0] = f.x; v[j * 4 + 1] = f.y; v[j * 4 + 2] = f.z; v[j * 4 + 3] = f.w;
  }
  float s = 0.f;
#pragma unroll
  for (int i = 0; i < 8; ++i) s += v[i];
  const float mean = wredsum(s) * (1.0f / 512.0f);
  float vs = 0.f;
#pragma unroll
  for (int i = 0; i < 8; ++i) { const float d = v[i] - mean; vs += d * d; }
  const float rstd = rsqrtf(wredsum(vs) * (1.0f / 512.0f) + 1e-5f);
#pragma unroll
  for (int j = 0; j < 2; ++j) {
    const int d = j * 256 + lane * 4;
    const float4 gv = *(const float4*)&g[d];
    const float4 bv = *(const float4*)&be[d];
    float4 o;
    o.x = (v[j * 4 + 0] - mean) * rstd * gv.x + bv.x;
    o.y = (v[j * 4 + 1] - mean) * rstd * gv.y + bv.y;
    o.z = (v[j * 4 + 2] - mean) * rstd * gv.z + bv.z;
    o.w = (v[j * 4 + 3] - mean) * rstd * gv.w + bv.w;
    *(float4*)&x[(size_t)row * DD + d] = o;
    short4_ ob;
    ob[0] = (short)f2b(o.x); ob[1] = (short)f2b(o.y);
    ob[2] = (short)f2b(o.z); ob[3] = (short)f2b(o.w);
    *(short4_*)&xb[(size_t)row * DD + d] = ob;
  }
}

// ---------------- MFMA GEMM: C = A[M,K](bf16) * Bt[N,K](bf16)^T + bias -------
// 128x128 tile, BK=64, 4 waves, each wave 64x64 via 4x4 16x16x32 frags.
// EPI: 0 f32 out+bias; 1 bf16 out+bias+relu; 2 f32 out+bias+residual;
//      5 fused QKV scatter (outv=q^T [B,H,DH,T], out2v=k [B,H,T,DH], out3v=v)
template <int EPI>
__global__ __launch_bounds__(256) void gemm_mfma(
    const unsigned short* __restrict__ A, const unsigned short* __restrict__ Bt,
    const float* __restrict__ bias, const float* __restrict__ bias2,
    const float* __restrict__ bias3, const float* __restrict__ res,
    void* __restrict__ outv, void* __restrict__ out2v, void* __restrict__ out3v,
    int M, int N, int K) {
  __shared__ unsigned short As[128 * 64];  // [m][k] with XOR-swizzled k-bytes
  __shared__ unsigned short Bs[128 * 64];  // [n][k] same
  const int tid = threadIdx.x;
  const int m0 = blockIdx.y * 128, n0 = blockIdx.x * 128;
  const int wid = tid >> 6, lane = tid & 63;
  const int wr = wid >> 1, wc = wid & 1;
  const int cl = lane & 15, rg = lane >> 4;
  f32x4 acc[4][4];
#pragma unroll
  for (int i = 0; i < 4; ++i)
#pragma unroll
    for (int j = 0; j < 4; ++j) acc[i][j] = (f32x4){0.f, 0.f, 0.f, 0.f};

  const int rbase = tid >> 3, sl = tid & 7;
  const int sc = 8 * (sl ^ (rbase & 7));  // pre-swizzled source column (elems)

  for (int k0 = 0; k0 < K; k0 += 64) {
    if (k0) __syncthreads();
#pragma unroll
    for (int i = 0; i < 4; ++i) {
      const int r = i * 32 + rbase;
      gl_lds16(A + (size_t)(m0 + r) * K + k0 + sc, (char*)As + (i * 256 + tid) * 16);
      gl_lds16(Bt + (size_t)(n0 + r) * K + k0 + sc, (char*)Bs + (i * 256 + tid) * 16);
    }
    __syncthreads();  // drains vmcnt(0): staged data visible
#pragma unroll
    for (int ks = 0; ks < 2; ++ks) {
      short8 a[4], b[4];
      const int kbyte = ks * 64 + rg * 16;
#pragma unroll
      for (int f = 0; f < 4; ++f) {
        const int am = wr * 64 + f * 16 + cl;
        a[f] = *(const short8*)((const char*)As + am * 128 + (kbyte ^ ((am & 7) << 4)));
        const int bn = wc * 64 + f * 16 + cl;
        b[f] = *(const short8*)((const char*)Bs + bn * 128 + (kbyte ^ ((bn & 7) << 4)));
      }
#pragma unroll
      for (int mi = 0; mi < 4; ++mi)
#pragma unroll
        for (int ni = 0; ni < 4; ++ni)
          acc[mi][ni] = __builtin_amdgcn_mfma_f32_16x16x32_bf16(a[mi], b[ni],
                                                                acc[mi][ni], 0, 0, 0);
    }
  }

#pragma unroll
  for (int ni = 0; ni < 4; ++ni) {
    const int n = n0 + wc * 64 + ni * 16 + cl;
    float bv;
    if constexpr (EPI == 5) {
      bv = (n < 512) ? bias[n] : (n < 1024 ? bias2[n - 512] : bias3[n - 1024]);
    } else {
      bv = bias[n];
    }
#pragma unroll
    for (int mi = 0; mi < 4; ++mi) {
#pragma unroll
      for (int i = 0; i < 4; ++i) {
        const int m = m0 + wr * 64 + mi * 16 + rg * 4 + i;
        float v = acc[mi][ni][i] + bv;
        if constexpr (EPI == 0) {
          ((float*)outv)[(size_t)m * N + n] = v;
        } else if constexpr (EPI == 1) {
          ((unsigned short*)outv)[(size_t)m * N + n] = f2b(fmaxf(v, 0.f));
        } else if constexpr (EPI == 2) {
          ((float*)outv)[(size_t)m * N + n] = v + res[(size_t)m * N + n];
        } else {  // EPI == 5: fused QKV scatter
          const int bb = m >> 8, t = m & 255;
          if (n < 512) {
            const int hh = n >> 6, d = n & 63;
            ((unsigned short*)outv)[(((size_t)(bb * HH + hh) * DH + d) << 8) + t] = f2b(v);
          } else if (n < 1024) {
            const int n2 = n - 512, hh = n2 >> 6, d = n2 & 63;
            ((unsigned short*)out2v)[(((size_t)(bb * HH + hh) * TT + t) << 6) + d] = f2b(v);
          } else {
            const int n2 = n - 1024, hh = n2 >> 6, d = n2 & 63;
            ((unsigned short*)out3v)[(((size_t)(bb * HH + hh) * TT + t) << 6) + d] = f2b(v);
          }
        }
      }
    }
  }
}

// ---------------- flash attention, one lane per query, LDS-tiled K/V --------
__global__ __launch_bounds__(256) void attn_k(const unsigned short* __restrict__ qt,
                                              const unsigned short* __restrict__ kb,
                                              const unsigned short* __restrict__ vb,
                                              const int* __restrict__ seq_len,
                                              unsigned short* __restrict__ cb) {
  __shared__ float Kf[64][68];
  __shared__ float Vf[64][68];
  const int bh = blockIdx.x;
  const int b = bh >> 3, h = bh & 7;
  const int t = threadIdx.x;
  const int len = seq_len[b];
  float q[DH];
  {
    const unsigned short* qp = qt + (size_t)bh * (DH * TT) + t;
#pragma unroll
    for (int d = 0; d < DH; ++d) q[d] = b2f(qp[d * TT]);
  }
  float ctx[DH];
#pragma unroll
  for (int d = 0; d < DH; ++d) ctx[d] = 0.f;
  float m = -3.0e38f, l = 0.f;
  const int skey = threadIdx.x >> 2, sd = (threadIdx.x & 3) * 16;
  for (int kt0 = 0; kt0 < len; kt0 += 64) {
    __syncthreads();
    {
      const unsigned short* kr = kb + ((size_t)bh * TT + kt0 + skey) * DH + sd;
      const unsigned short* vr = vb + ((size_t)bh * TT + kt0 + skey) * DH + sd;
      short8 ka = *(const short8*)kr, kc2 = *(const short8*)(kr + 8);
      short8 va = *(const short8*)vr, vc2 = *(const short8*)(vr + 8);
#pragma unroll
      for (int j = 0; j < 8; ++j) {
        Kf[skey][sd + j] = b2f((unsigned short)ka[j]);
        Kf[skey][sd + 8 + j] = b2f((unsigned short)kc2[j]);
        Vf[skey][sd + j] = b2f((unsigned short)va[j]);
        Vf[skey][sd + 8 + j] = b2f((unsigned short)vc2[j]);
      }
    }
    __syncthreads();
    const int kend = min(64, len - kt0);
    for (int kk = 0; kk < kend; ++kk) {
      const float* krow = &Kf[kk][0];
      float s0 = 0.f, s1 = 0.f, s2 = 0.f, s3 = 0.f;
#pragma unroll
      for (int d = 0; d < DH; d += 4) {
        const float4 kv = *(const float4*)&krow[d];
        s0 += q[d + 0] * kv.x; s1 += q[d + 1] * kv.y;
        s2 += q[d + 2] * kv.z; s3 += q[d + 3] * kv.w;
      }
      const float s = ((s0 + s1) + (s2 + s3)) * 0.125f;
      if (s > m + 8.0f) {  // defer-max rescale (T13)
        const float scl = __expf(m - s);
        m = s; l *= scl;
#pragma unroll
        for (int d = 0; d < DH; ++d) ctx[d] *= scl;
      }
      const float p = __expf(s - m);
      l += p;
      const float* vrow = &Vf[kk][0];
#pragma unroll
      for (int d = 0; d < DH; d += 4) {
        const float4 vv = *(const float4*)&vrow[d];
        ctx[d + 0] += p * vv.x; ctx[d + 1] += p * vv.y;
        ctx[d + 2] += p * vv.z; ctx[d + 3] += p * vv.w;
      }
    }
  }
  const float rl = 1.0f / l;
  unsigned short* op = cb + ((size_t)(b * TT + t)) * DD + h * DH;
#pragma unroll
  for (int d = 0; d < DH; d += 8) {
    short8 o;
#pragma unroll
    for (int j = 0; j < 8; ++j) o[j] = (short)f2b(ctx[d + j] * rl);
    *(short8*)&op[d] = o;
  }
}

// ---------------- row LayerNorm, dual f32/bf16 out --------------------------
template <int MODE>
__global__ __launch_bounds__(64) void ln_k(const float* __restrict__ a,
                                           const float* __restrict__ b2,
                                           const float* __restrict__ g,
                                           const float* __restrict__ be,
                                           const int* __restrict__ seq_len,
                                           float* __restrict__ out,
                                           unsigned short* __restrict__ outb) {
  const int row = blockIdx.x, lane = threadIdx.x;
  float v[8];
#pragma unroll
  for (int j = 0; j < 2; ++j) {
    const int d = j * 256 + lane * 4;
    float4 f = *(const float4*)&a[(size_t)row * DD + d];
    if constexpr (MODE == 0) {
      const float4 f2 = *(const float4*)&b2[(size_t)row * DD + d];
      f.x += f2.x; f.y += f2.y; f.z += f2.z; f.w += f2.w;
    }
    v[j * 4 + 0] = f.x; v[j * 4 + 1] = f.y; v[j * 4 + 2] = f.z; v[j * 4 + 3] = f.w;
  }
  float s = 0.f;
#pragma unroll
  for (int i = 0; i < 8; ++i) s += v[i];
  const float mean = wredsum(s) * (1.0f / 512.0f);
  float vs = 0.f;
#pragma unroll
  for (int i = 0; i < 8; ++i) { const float d = v[i] - mean; vs += d * d; }
  const float rstd = rsqrtf(wredsum(vs) * (1.0f / 512.0f) + 1e-5f);
  float msk = 1.0f;
  if constexpr (MODE == 1) msk = ((row & 255) < seq_len[row >> 8]) ? 1.0f : 0.0f;
#pragma unroll
  for (int j = 0; j < 2; ++j) {
    const int d = j * 256 + lane * 4;
    const float4 gv = *(const float4*)&g[d];
    const float4 bv = *(const float4*)&be[d];
    float4 o;
    o.x = ((v[j * 4 + 0] - mean) * rstd * gv.x + bv.x) * msk;
    o.y = ((v[j * 4 + 1] - mean) * rstd * gv.y + bv.y) * msk;
    o.z = ((v[j * 4 + 2] - mean) * rstd * gv.z + bv.z) * msk;
    o.w = ((v[j * 4 + 3] - mean) * rstd * gv.w + bv.w) * msk;
    *(float4*)&out[(size_t)row * DD + d] = o;
    short4_ ob;
    ob[0] = (short)f2b(o.x); ob[1] = (short)f2b(o.y);
    ob[2] = (short)f2b(o.z); ob[3] = (short)f2b(o.w);
    *(short4_*)&outb[(size_t)row * DD + d] = ob;
  }
}

// ---------------- logits = x @ Wout + bout,  N=25 ---------------------------
__global__ __launch_bounds__(256) void logits_k(const float* __restrict__ x,
                                                const float* __restrict__ W,
                                                const float* __restrict__ bo,
                                                float* __restrict__ lg) {
  __shared__ float xs[8][516];
  const int r0 = blockIdx.x * 8;
  for (int i = threadIdx.x; i < 1024; i += 256) {
    const int rr = i >> 7, c4 = i & 127;
    *(float4*)&xs[rr][c4 * 4] = *(const float4*)&x[(size_t)(r0 + rr) * DD + c4 * 4];
  }
  __syncthreads();
  const int r = threadIdx.x >> 5, c = threadIdx.x & 31;
  if (c < CC) {
    float acc = 0.f;
#pragma unroll 8
    for (int k = 0; k < DD; ++k) acc += xs[r][k] * W[k * CC + c];
    lg[(size_t)(r0 + r) * CC + c] = acc + bo[c];
  }
}

// ---------------- CRF: linear-domain scan (log_z) + gold score --------------
// alpha recursion in linear domain: A_j = exp(alpha_j - M).
// step: A'_j = (sum_i A_i * exp(trans[i][j])) * exp(emit[t][j]); renorm by A_0
// every 4 steps (M += log(A_0)). Mathematically exact; no per-step exp/log.
__global__ __launch_bounds__(64) void crf_k(const float* __restrict__ lg,
                                            const int* __restrict__ tag,
                                            const int* __restrict__ seq_len,
                                            const float* __restrict__ trans,
                                            float* __restrict__ nll) {
  __shared__ float eexp[TT * CC + 64];  // exp(emit), +64 slop for lanes >= CC
  __shared__ float tr[CC * CC];
  const int b = blockIdx.x;
  const int l = threadIdx.x;
  const float* lgb = lg + (size_t)b * TT * CC;
  for (int i = l; i < TT * CC; i += 64) eexp[i] = __expf(lgb[i]);
  for (int i = l; i < CC * CC; i += 64) tr[i] = trans[i];
  __syncthreads();
  const int len = seq_len[b];
  const int lc = (l < CC) ? l : (CC - 1);
  float et[CC];  // exp of trans column lc
#pragma unroll
  for (int i = 0; i < CC; ++i) et[i] = __expf(tr[i * CC + lc]);
  const float e00 = lgb[0];  // uniform -> scalar load
  float M = e00;
  float A = (l < CC) ? __expf(lgb[l] - e00) : 0.f;
  for (int t = 1; t < len; ++t) {
    float s0 = 0.f, s1 = 0.f, s2 = 0.f, s3 = 0.f, s4 = 0.f;
#pragma unroll
    for (int i = 0; i < CC; i += 5) {
      s0 += __shfl(A, i + 0, 64) * et[i + 0];
      s1 += __shfl(A, i + 1, 64) * et[i + 1];
      s2 += __shfl(A, i + 2, 64) * et[i + 2];
      s3 += __shfl(A, i + 3, 64) * et[i + 3];
      s4 += __shfl(A, i + 4, 64) * et[i + 4];
    }
    A = (((s0 + s1) + (s2 + s3)) + s4) * eexp[t * CC + lc];
    if ((t & 3) == 0) {
      const float r = __shfl(A, 0, 64);  // A_0 > 0 always (dense transitions)
      M += __logf(r);
      A *= __builtin_amdgcn_rcpf(r);
    }
  }
  const float tot = wredsum((l < CC) ? A : 0.f);
  float gold = 0.f;
  for (int t = l; t < TT; t += 64)
    if (t < len) gold += lgb[t * CC + tag[b * TT + t]];
  for (int t = 1 + l; t < TT; t += 64)
    if (t < len) gold += tr[tag[b * TT + t - 1] * CC + tag[b * TT + t]];
  gold = wredsum(gold);
  if (l == 0) nll[b] = (M + __logf(tot)) - gold;
}

__global__ __launch_bounds__(64) void final_k(const float* __restrict__ nll,
                                              float* __restrict__ out) {
  float v = nll[threadIdx.x];
  v = wredsum(v);
  if (threadIdx.x == 0) out[0] = v * (1.0f / 64.0f);
}

}  // namespace

extern "C" void kernel_launch(void* const* d_in, const int* in_sizes, int n_in,
                              void* d_out, int out_size, void* d_ws, size_t ws_size,
                              hipStream_t stream) {
  (void)in_sizes; (void)n_in; (void)out_size; (void)ws_size;
  const int* chi = (const int*)d_in[0];
  const int* wdi = (const int*)d_in[1];
  const int* psi = (const int*)d_in[2];
  const float* spo = (const float*)d_in[3];
  const int* seq_len = (const int*)d_in[4];
  const int* tag = (const int*)d_in[5];
  const float* ctab = (const float*)d_in[6];
  const float* wtab = (const float*)d_in[7];
  const float* ptab = (const float*)d_in[8];
  const float* ln0g = (const float*)d_in[9];
  const float* ln0b = (const float*)d_in[10];
  const float* Wq = (const float*)d_in[11];
  const float* bq = (const float*)d_in[12];
  const float* Wk = (const float*)d_in[13];
  const float* bk = (const float*)d_in[14];
  const float* Wv = (const float*)d_in[15];
  const float* bv = (const float*)d_in[16];
  const float* Wo = (const float*)d_in[17];
  const float* bo = (const float*)d_in[18];
  const float* ln1g = (const float*)d_in[19];
  const float* ln1b = (const float*)d_in[20];
  const float* W1 = (const float*)d_in[21];
  const float* b1 = (const float*)d_in[22];
  const float* W2 = (const float*)d_in[23];
  const float* b2 = (const float*)d_in[24];
  const float* ln2g = (const float*)d_in[25];
  const float* ln2b = (const float*)d_in[26];
  const float* Wout = (const float*)d_in[27];
  const float* bout = (const float*)d_in[28];
  const float* trans = (const float*)d_in[29];

  // ---- workspace layout (~187 MB) ----
  char* w8 = (char*)d_ws;
  float* x = (float*)(w8);                              // 32MB f32 activations
  float* t0 = (float*)(w8 + 32 * MB);                   // 32MB ffn-out f32
  unsigned short* cb = (unsigned short*)t0;             // ctx bf16 (dead before t0 write)
  float* h1f = (float*)(w8 + 64 * MB);                  // 32MB h1 f32
  unsigned short* xb = (unsigned short*)(w8 + 96 * MB); // 16MB x bf16
  unsigned short* qt = (unsigned short*)(w8 + 112 * MB);// 16MB q^T bf16 [B,H,DH,T]
  unsigned short* ib = qt;                              // 32MB ffn inner bf16 (qt+kb)
  unsigned short* kb = (unsigned short*)(w8 + 128 * MB);// 16MB k bf16 [B,H,T,DH]
  unsigned short* vb = (unsigned short*)(w8 + 144 * MB);// 16MB v bf16
  unsigned short* hb = vb;                              // h1 bf16 (vb dead post-attn)
  unsigned short* wqkv = (unsigned short*)(w8 + 160 * MB);  // [L][1536][512] 6MB
  unsigned short* wot = (unsigned short*)(w8 + 166 * MB);   // [L][512][512] 2MB
  unsigned short* w1t = (unsigned short*)(w8 + 168 * MB);   // [L][2048][512] 8MB
  unsigned short* w2t = (unsigned short*)(w8 + 176 * MB);   // [L][512][2048] 8MB
  float* lg = (float*)(w8 + 184 * MB);
  float* nll = (float*)(w8 + 186 * MB);

  // weight f32 [K,N] -> bf16 [N,K]; QKV packed into one [1536][512] slab/layer
  const size_t QKVS = (size_t)1536 * 512;
  wconv_k<<<dim3(8, 8, LT), 256, 0, stream>>>(Wq, wqkv, DD, DD, QKVS);
  wconv_k<<<dim3(8, 8, LT), 256, 0, stream>>>(Wk, wqkv + 512 * 512, DD, DD, QKVS);
  wconv_k<<<dim3(8, 8, LT), 256, 0, stream>>>(Wv, wqkv + 1024 * 512, DD, DD, QKVS);
  wconv_k<<<dim3(8, 8, LT), 256, 0, stream>>>(Wo, wot, DD, DD, (size_t)DD * DD);
  wconv_k<<<dim3(8, 32, LT), 256, 0, stream>>>(W1, w1t, DD, FF, (size_t)DD * FF);
  wconv_k<<<dim3(32, 8, LT), 256, 0, stream>>>(W2, w2t, FF, DD, (size_t)FF * DD);

  embed_ln0_k<<<M_ALL, 64, 0, stream>>>(chi, wdi, psi, spo, ctab, wtab, ptab,
                                        ln0g, ln0b, x, xb);

  for (int l = 0; l < LT; ++l) {
    gemm_mfma<5><<<dim3(12, 128), 256, 0, stream>>>(
        xb, wqkv + (size_t)l * QKVS, bq + l * DD, bk + l * DD, bv + l * DD,
        nullptr, qt, kb, vb, M_ALL, 1536, DD);
    attn_k<<<BB * HH, TT, 0, stream>>>(qt, kb, vb, seq_len, cb);
    gemm_mfma<0><<<dim3(4, 128), 256, 0, stream>>>(
        cb, wot + (size_t)l * DD * DD, bo + l * DD, nullptr, nullptr, nullptr,
        h1f, nullptr, nullptr, M_ALL, DD, DD);
    ln_k<0><<<M_ALL, 64, 0, stream>>>(h1f, x, ln1g + l * DD, ln1b + l * DD,
                                      nullptr, h1f, hb);
    for (int c = 0; c < 2; ++c) {  // 2 x 8192-row chunks (inner aliases qt+kb)
      const size_t ro = (size_t)c * 8192 * DD;
      gemm_mfma<1><<<dim3(FF / 128, 8192 / 128), 256, 0, stream>>>(
          hb + ro, w1t + (size_t)l * FF * DD, b1 + l * FF, nullptr, nullptr,
          nullptr, ib, nullptr, nullptr, 8192, FF, DD);
      gemm_mfma<2><<<dim3(DD / 128, 8192 / 128), 256, 0, stream>>>(
          ib, w2t + (size_t)l * FF * DD, b2 + l * DD, nullptr, nullptr,
          h1f + ro, t0 + ro, nullptr, nullptr, 8192, DD, FF);
    }
    ln_k<1><<<M_ALL, 64, 0, stream>>>(t0, nullptr, ln2g + l * DD, ln2b + l * DD,
                                      seq_len, x, xb);
  }
  logits_k<<<M_ALL / 8, 256, 0, stream>>>(x, Wout, bout, lg);
  crf_k<<<BB, 64, 0, stream>>>(lg, tag, seq_len, trans, nll);
  final_k<<<1, 64, 0, stream>>>(nll, (float*)d_out);
}

// Round 4
// 1196.462 us; speedup vs baseline: 6.8852x; 1.5128x over previous
//
#include <hip/hip_runtime.h>
#include <cmath>

namespace {

constexpr int LT = 4;       // layers
constexpr int BB = 64;      // batch
constexpr int TT = 256;     // seq len
constexpr int DD = 512;     // model dim
constexpr int HH = 8;       // heads
constexpr int DH = 64;      // head dim
constexpr int FF = 2048;    // ffn inner
constexpr int CC = 25;      // tag classes
constexpr int M_ALL = BB * TT;   // 16384 token rows
constexpr size_t MB = 1024 * 1024;

typedef __attribute__((ext_vector_type(8))) short short8;
typedef __attribute__((ext_vector_type(4))) short short4_;
typedef __attribute__((ext_vector_type(4))) float f32x4;
typedef __attribute__((ext_vector_type(4))) _Float16 half4;

__device__ __forceinline__ float b2f(unsigned short u) {
  union { unsigned int i; float f; } x; x.i = ((unsigned int)u) << 16; return x.f;
}
__device__ __forceinline__ unsigned short f2b(float f) {
  union { float f; unsigned int i; } x; x.f = f;
  unsigned int r = x.i + 0x7FFFu + ((x.i >> 16) & 1u);
  return (unsigned short)(r >> 16);
}
__device__ __forceinline__ void gl_lds16(const void* g, void* l) {
  __builtin_amdgcn_global_load_lds(
      (const __attribute__((address_space(1))) unsigned int*)g,
      (__attribute__((address_space(3))) unsigned int*)l, 16, 0, 0);
}
__device__ __forceinline__ float wredsum(float v) {
#pragma unroll
  for (int o = 32; o > 0; o >>= 1) v += __shfl_xor(v, o, 64);
  return v;
}

// ---------------- weight convert+transpose: in [K,N] f32 -> out [N,K] bf16 ---
__global__ __launch_bounds__(256) void wconv_k(const float* __restrict__ in,
                                               unsigned short* __restrict__ out,
                                               int K, int N, size_t lstride) {
  __shared__ float ts[64][65];
  const int k0 = blockIdx.x * 64, n0 = blockIdx.y * 64;
  in += (size_t)blockIdx.z * K * N;
  out += (size_t)blockIdx.z * lstride;
  const int tid = threadIdx.x;
  for (int i = tid; i < 1024; i += 256) {
    const int r = i >> 4, c4 = i & 15;
    const float4 f = *(const float4*)&in[(size_t)(k0 + r) * N + n0 + c4 * 4];
    ts[r][c4 * 4 + 0] = f.x; ts[r][c4 * 4 + 1] = f.y;
    ts[r][c4 * 4 + 2] = f.z; ts[r][c4 * 4 + 3] = f.w;
  }
  __syncthreads();
  const int n_r = tid >> 2, kc = (tid & 3) * 16;
  short8 v0, v1;
#pragma unroll
  for (int j = 0; j < 8; ++j) {
    v0[j] = (short)f2b(ts[kc + j][n_r]);
    v1[j] = (short)f2b(ts[kc + 8 + j][n_r]);
  }
  unsigned short* op = out + (size_t)(n0 + n_r) * K + k0 + kc;
  *(short8*)op = v0;
  *(short8*)(op + 8) = v1;
}

// ---------------- embed (char|word|pos|spo concat) + LN0, dual f32/bf16 out --
__global__ __launch_bounds__(64) void embed_ln0_k(
    const int* __restrict__ ch, const int* __restrict__ wd, const int* __restrict__ ps,
    const float* __restrict__ spo, const float* __restrict__ ctab,
    const float* __restrict__ wtab, const float* __restrict__ ptab,
    const float* __restrict__ g, const float* __restrict__ be,
    float* __restrict__ x, unsigned short* __restrict__ xb) {
  const int row = blockIdx.x;
  const int lane = threadIdx.x;
  const int b = row >> 8;
  const int ci = ch[row], wi = wd[row], pi = ps[row];
  float v[8];
#pragma unroll
  for (int j = 0; j < 2; ++j) {
    const int d = j * 256 + lane * 4;
    float4 f;
    if (d < 128)      f = *(const float4*)&ctab[(size_t)ci * 128 + d];
    else if (d < 428) f = *(const float4*)&wtab[(size_t)wi * 300 + (d - 128)];
    else if (d < 492) f = *(const float4*)&ptab[(size_t)pi * 64 + (d - 428)];
    else              f = *(const float4*)&spo[(size_t)b * 20 + (d - 492)];
    v[j * 4 + 0] = f.x; v[j * 4 + 1] = f.y; v[j * 4 + 2] = f.z; v[j * 4 + 3] = f.w;
  }
  float s = 0.f;
#pragma unroll
  for (int i = 0; i < 8; ++i) s += v[i];
  const float mean = wredsum(s) * (1.0f / 512.0f);
  float vs = 0.f;
#pragma unroll
  for (int i = 0; i < 8; ++i) { const float d = v[i] - mean; vs += d * d; }
  const float rstd = rsqrtf(wredsum(vs) * (1.0f / 512.0f) + 1e-5f);
#pragma unroll
  for (int j = 0; j < 2; ++j) {
    const int d = j * 256 + lane * 4;
    const float4 gv = *(const float4*)&g[d];
    const float4 bv = *(const float4*)&be[d];
    float4 o;
    o.x = (v[j * 4 + 0] - mean) * rstd * gv.x + bv.x;
    o.y = (v[j * 4 + 1] - mean) * rstd * gv.y + bv.y;
    o.z = (v[j * 4 + 2] - mean) * rstd * gv.z + bv.z;
    o.w = (v[j * 4 + 3] - mean) * rstd * gv.w + bv.w;
    *(float4*)&x[(size_t)row * DD + d] = o;
    short4_ ob;
    ob[0] = (short)f2b(o.x); ob[1] = (short)f2b(o.y);
    ob[2] = (short)f2b(o.z); ob[3] = (short)f2b(o.w);
    *(short4_*)&xb[(size_t)row * DD + d] = ob;
  }
}

// ---------------- MFMA GEMM: C = A[M,K](bf16) * Bt[N,K](bf16)^T + bias -------
// EPI: 0 f32 out+bias; 1 bf16 out+bias+relu; 2 f32 out+bias+residual;
//      5 fused QKV scatter: q->[B,H,T,DH]bf16, k->[B,H,T,DH]bf16, v->[B,H,DH,T]f16
template <int EPI>
__global__ __launch_bounds__(256) void gemm_mfma(
    const unsigned short* __restrict__ A, const unsigned short* __restrict__ Bt,
    const float* __restrict__ bias, const float* __restrict__ bias2,
    const float* __restrict__ bias3, const float* __restrict__ res,
    void* __restrict__ outv, void* __restrict__ out2v, void* __restrict__ out3v,
    int M, int N, int K) {
  __shared__ unsigned short As[128 * 64];
  __shared__ unsigned short Bs[128 * 64];
  const int tid = threadIdx.x;
  const int m0 = blockIdx.y * 128, n0 = blockIdx.x * 128;
  const int wid = tid >> 6, lane = tid & 63;
  const int wr = wid >> 1, wc = wid & 1;
  const int cl = lane & 15, rg = lane >> 4;
  f32x4 acc[4][4];
#pragma unroll
  for (int i = 0; i < 4; ++i)
#pragma unroll
    for (int j = 0; j < 4; ++j) acc[i][j] = (f32x4){0.f, 0.f, 0.f, 0.f};

  const int rbase = tid >> 3, sl = tid & 7;
  const int sc = 8 * (sl ^ (rbase & 7));

  for (int k0 = 0; k0 < K; k0 += 64) {
    if (k0) __syncthreads();
#pragma unroll
    for (int i = 0; i < 4; ++i) {
      const int r = i * 32 + rbase;
      gl_lds16(A + (size_t)(m0 + r) * K + k0 + sc, (char*)As + (i * 256 + tid) * 16);
      gl_lds16(Bt + (size_t)(n0 + r) * K + k0 + sc, (char*)Bs + (i * 256 + tid) * 16);
    }
    __syncthreads();
#pragma unroll
    for (int ks = 0; ks < 2; ++ks) {
      short8 a[4], b[4];
      const int kbyte = ks * 64 + rg * 16;
#pragma unroll
      for (int f = 0; f < 4; ++f) {
        const int am = wr * 64 + f * 16 + cl;
        a[f] = *(const short8*)((const char*)As + am * 128 + (kbyte ^ ((am & 7) << 4)));
        const int bn = wc * 64 + f * 16 + cl;
        b[f] = *(const short8*)((const char*)Bs + bn * 128 + (kbyte ^ ((bn & 7) << 4)));
      }
#pragma unroll
      for (int mi = 0; mi < 4; ++mi)
#pragma unroll
        for (int ni = 0; ni < 4; ++ni)
          acc[mi][ni] = __builtin_amdgcn_mfma_f32_16x16x32_bf16(a[mi], b[ni],
                                                                acc[mi][ni], 0, 0, 0);
    }
  }

#pragma unroll
  for (int ni = 0; ni < 4; ++ni) {
    const int n = n0 + wc * 64 + ni * 16 + cl;
    float bv;
    if constexpr (EPI == 5) {
      bv = (n < 512) ? bias[n] : (n < 1024 ? bias2[n - 512] : bias3[n - 1024]);
    } else {
      bv = bias[n];
    }
#pragma unroll
    for (int mi = 0; mi < 4; ++mi) {
      if constexpr (EPI == 5) {
        const int mb = m0 + wr * 64 + mi * 16 + rg * 4;
        const int bb = mb >> 8, t0v = mb & 255;  // i=0..3 stays in same 256-block
        if (n < 1024) {
          const int n2 = n & 511, hh = n2 >> 6, d = n2 & 63;
          unsigned short* outp = (unsigned short*)((n < 512) ? outv : out2v);
#pragma unroll
          for (int i = 0; i < 4; ++i)
            outp[(((size_t)(bb * HH + hh) * TT + t0v + i) << 6) + d] =
                f2b(acc[mi][ni][i] + bv);
        } else {
          const int n2 = n - 1024, hh = n2 >> 6, d = n2 & 63;
          half4 pk;
#pragma unroll
          for (int i = 0; i < 4; ++i) pk[i] = (_Float16)(acc[mi][ni][i] + bv);
          *(half4*)((_Float16*)out3v + (((size_t)(bb * HH + hh) * DH + d) << 8) + t0v) = pk;
        }
      } else {
#pragma unroll
        for (int i = 0; i < 4; ++i) {
          const int m = m0 + wr * 64 + mi * 16 + rg * 4 + i;
          float v = acc[mi][ni][i] + bv;
          if constexpr (EPI == 0) {
            ((float*)outv)[(size_t)m * N + n] = v;
          } else if constexpr (EPI == 1) {
            ((unsigned short*)outv)[(size_t)m * N + n] = f2b(fmaxf(v, 0.f));
          } else if constexpr (EPI == 2) {
            ((float*)outv)[(size_t)m * N + n] = v + res[(size_t)m * N + n];
          }
        }
      }
    }
  }
}

// ---------------- MFMA flash attention --------------------------------------
// qb/kb [B,H,T,DH] bf16, vt [B,H,DH,T] f16, out cb [B,T,H*DH] bf16.
// Block = one (b,h), 4 waves; wave = 16 queries/tile, 4 tiles.
// S^T = mfma_16x16x32_bf16(K,Q) -> C-frag (row=k, col=q) feeds directly as
// B-frag of mfma_16x16x16f16 for PV (k = rg*4+i matches both layouts).
__global__ __launch_bounds__(256) void attn_mfma_k(
    const unsigned short* __restrict__ qb, const unsigned short* __restrict__ kbp,
    const _Float16* __restrict__ vtp, const int* __restrict__ seq_len,
    unsigned short* __restrict__ cb) {
  __shared__ unsigned short Ks[256 * 64];  // [t][d] bf16, 16B-slot XOR swizzle
  __shared__ _Float16 Vs[64 * 256];        // [d][t] f16, swizzled
  __shared__ unsigned short Os[64 * 64];   // out transpose stage, swizzled
  const int bh = blockIdx.x;
  const int b = bh >> 3, h = bh & 7;
  const int tid = threadIdx.x;
  const int wid = tid >> 6, lane = tid & 63;
  const int cl = lane & 15, rg = lane >> 4;
  const int len = seq_len[b];

  {  // stage K (32KB) and V^T (32KB), pre-swizzled source -> linear LDS
    const int r = tid >> 3, sl = tid & 7;
#pragma unroll
    for (int i = 0; i < 8; ++i) {
      const int row = i * 32 + r;
      gl_lds16(kbp + ((size_t)bh * TT + row) * DH + 8 * (sl ^ (row & 7)),
               (char*)Ks + (i * 256 + tid) * 16);
    }
#pragma unroll
    for (int i = 0; i < 8; ++i) {
      const int u = i * 256 + tid;
      const int vrow = u >> 5, vsl = u & 31;
      gl_lds16(vtp + ((size_t)bh * DH + vrow) * TT + 8 * (vsl ^ (vrow & 7)),
               (char*)Vs + u * 16);
    }
  }
  __syncthreads();

  for (int qt4 = 0; qt4 < 4; ++qt4) {
    f32x4 o[4];
#pragma unroll
    for (int db = 0; db < 4; ++db) o[db] = (f32x4){0.f, 0.f, 0.f, 0.f};
    if (qt4 * 64 < len) {  // block-uniform
      const int q0 = qt4 * 64 + wid * 16;
      short8 bqf[2];
      const unsigned short* qp = qb + ((size_t)bh * TT + q0 + cl) * DH + rg * 8;
      bqf[0] = *(const short8*)qp;
      bqf[1] = *(const short8*)(qp + 32);
      f32x4 s[16];
#pragma unroll
      for (int kk = 0; kk < 16; ++kk) {
        s[kk] = (f32x4){0.f, 0.f, 0.f, 0.f};
        if (kk * 16 < len) {
          const int row = kk * 16 + cl;
          const char* base = (const char*)Ks + row * 128;
          const int sw = (row & 7) << 4;
          const short8 a0 = *(const short8*)(base + ((rg * 16) ^ sw));
          const short8 a1 = *(const short8*)(base + ((64 + rg * 16) ^ sw));
          s[kk] = __builtin_amdgcn_mfma_f32_16x16x32_bf16(a0, bqf[0], s[kk], 0, 0, 0);
          s[kk] = __builtin_amdgcn_mfma_f32_16x16x32_bf16(a1, bqf[1], s[kk], 0, 0, 0);
        }
      }
      // in-register softmax per q (q = cl; lane holds keys kk*16 + rg*4 + i)
      float mx = -3.0e38f;
#pragma unroll
      for (int kk = 0; kk < 16; ++kk)
        if (kk * 16 < len) {
#pragma unroll
          for (int i = 0; i < 4; ++i) {
            float v = s[kk][i] * 0.125f;
            v = (kk * 16 + rg * 4 + i < len) ? v : -3.0e38f;
            s[kk][i] = v;
            mx = fmaxf(mx, v);
          }
        }
      mx = fmaxf(mx, __shfl_xor(mx, 16, 64));
      mx = fmaxf(mx, __shfl_xor(mx, 32, 64));
      float lsum = 0.f;
#pragma unroll
      for (int kk = 0; kk < 16; ++kk)
        if (kk * 16 < len) {
#pragma unroll
          for (int i = 0; i < 4; ++i) {
            const float p = __expf(s[kk][i] - mx);
            s[kk][i] = p;
            lsum += p;
          }
        }
      lsum += __shfl_xor(lsum, 16, 64);
      lsum += __shfl_xor(lsum, 32, 64);
      const float rl = 1.0f / lsum;
      // PV: ctx^T[d][q] += V^T[d][k] * P^T[k][q]
#pragma unroll
      for (int kk = 0; kk < 16; ++kk)
        if (kk * 16 < len) {
          half4 bp;
#pragma unroll
          for (int i = 0; i < 4; ++i) bp[i] = (_Float16)(s[kk][i] * rl);
#pragma unroll
          for (int db = 0; db < 4; ++db) {
            const int vrow = db * 16 + cl;
            const int byte = kk * 32 + rg * 8;
            const half4 a = *(const half4*)((const char*)Vs + vrow * 512 +
                              ((byte & ~15) ^ ((vrow & 7) << 4)) + (byte & 15));
            o[db] = __builtin_amdgcn_mfma_f32_16x16x16f16(a, bp, o[db], 0, 0, 0);
          }
        }
    }
    __syncthreads();  // Os free (prev copy done)
    {
      const int orow = wid * 16 + cl;
      char* obase = (char*)Os + orow * 128;
      const int sw = (orow & 7) << 4;
#pragma unroll
      for (int db = 0; db < 4; ++db) {
        short4_ pk;
#pragma unroll
        for (int i = 0; i < 4; ++i) pk[i] = (short)f2b(o[db][i]);
        const int byte = db * 32 + rg * 8;
        *(short4_*)(obase + ((byte & ~15) ^ sw) + (byte & 15)) = pk;
      }
    }
    __syncthreads();
    {  // coalesced copy Os (64q x 64d bf16) -> cb
      const int r = tid >> 2, part = tid & 3;
      const int sw = (r & 7) << 4;
      const char* rbase = (const char*)Os + r * 128;
      const short8 w0 = *(const short8*)(rbase + ((part * 32) ^ sw));
      const short8 w1 = *(const short8*)(rbase + ((part * 32 + 16) ^ sw));
      unsigned short* dst = cb + ((size_t)(b * TT + qt4 * 64 + r)) * DD + h * DH + part * 16;
      *(short8*)dst = w0;
      *(short8*)(dst + 8) = w1;
    }
  }
}

// ---------------- row LayerNorm, dual f32/bf16 out --------------------------
template <int MODE>
__global__ __launch_bounds__(64) void ln_k(const float* __restrict__ a,
                                           const float* __restrict__ b2,
                                           const float* __restrict__ g,
                                           const float* __restrict__ be,
                                           const int* __restrict__ seq_len,
                                           float* __restrict__ out,
                                           unsigned short* __restrict__ outb) {
  const int row = blockIdx.x, lane = threadIdx.x;
  float v[8];
#pragma unroll
  for (int j = 0; j < 2; ++j) {
    const int d = j * 256 + lane * 4;
    float4 f = *(const float4*)&a[(size_t)row * DD + d];
    if constexpr (MODE == 0) {
      const float4 f2 = *(const float4*)&b2[(size_t)row * DD + d];
      f.x += f2.x; f.y += f2.y; f.z += f2.z; f.w += f2.w;
    }
    v[j * 4 + 0] = f.x; v[j * 4 + 1] = f.y; v[j * 4 + 2] = f.z; v[j * 4 + 3] = f.w;
  }
  float s = 0.f;
#pragma unroll
  for (int i = 0; i < 8; ++i) s += v[i];
  const float mean = wredsum(s) * (1.0f / 512.0f);
  float vs = 0.f;
#pragma unroll
  for (int i = 0; i < 8; ++i) { const float d = v[i] - mean; vs += d * d; }
  const float rstd = rsqrtf(wredsum(vs) * (1.0f / 512.0f) + 1e-5f);
  float msk = 1.0f;
  if constexpr (MODE == 1) msk = ((row & 255) < seq_len[row >> 8]) ? 1.0f : 0.0f;
#pragma unroll
  for (int j = 0; j < 2; ++j) {
    const int d = j * 256 + lane * 4;
    const float4 gv = *(const float4*)&g[d];
    const float4 bv = *(const float4*)&be[d];
    float4 o;
    o.x = ((v[j * 4 + 0] - mean) * rstd * gv.x + bv.x) * msk;
    o.y = ((v[j * 4 + 1] - mean) * rstd * gv.y + bv.y) * msk;
    o.z = ((v[j * 4 + 2] - mean) * rstd * gv.z + bv.z) * msk;
    o.w = ((v[j * 4 + 3] - mean) * rstd * gv.w + bv.w) * msk;
    *(float4*)&out[(size_t)row * DD + d] = o;
    short4_ ob;
    ob[0] = (short)f2b(o.x); ob[1] = (short)f2b(o.y);
    ob[2] = (short)f2b(o.z); ob[3] = (short)f2b(o.w);
    *(short4_*)&outb[(size_t)row * DD + d] = ob;
  }
}

// ---------------- logits = x @ Wout + bout,  N=25 ---------------------------
__global__ __launch_bounds__(256) void logits_k(const float* __restrict__ x,
                                                const float* __restrict__ W,
                                                const float* __restrict__ bo,
                                                float* __restrict__ lg) {
  __shared__ float xs[8][516];
  const int r0 = blockIdx.x * 8;
  for (int i = threadIdx.x; i < 1024; i += 256) {
    const int rr = i >> 7, c4 = i & 127;
    *(float4*)&xs[rr][c4 * 4] = *(const float4*)&x[(size_t)(r0 + rr) * DD + c4 * 4];
  }
  __syncthreads();
  const int r = threadIdx.x >> 5, c = threadIdx.x & 31;
  if (c < CC) {
    float acc = 0.f;
#pragma unroll 8
    for (int k = 0; k < DD; ++k) acc += xs[r][k] * W[k * CC + c];
    lg[(size_t)(r0 + r) * CC + c] = acc + bo[c];
  }
}

// ---------------- CRF: linear-domain scan (log_z) + gold score --------------
__global__ __launch_bounds__(64) void crf_k(const float* __restrict__ lg,
                                            const int* __restrict__ tag,
                                            const int* __restrict__ seq_len,
                                            const float* __restrict__ trans,
                                            float* __restrict__ nll) {
  __shared__ float eexp[TT * CC + 64];
  __shared__ float tr[CC * CC];
  const int b = blockIdx.x;
  const int l = threadIdx.x;
  const float* lgb = lg + (size_t)b * TT * CC;
  for (int i = l; i < TT * CC; i += 64) eexp[i] = __expf(lgb[i]);
  for (int i = l; i < CC * CC; i += 64) tr[i] = trans[i];
  __syncthreads();
  const int len = seq_len[b];
  const int lc = (l < CC) ? l : (CC - 1);
  float et[CC];
#pragma unroll
  for (int i = 0; i < CC; ++i) et[i] = __expf(tr[i * CC + lc]);
  const float e00 = lgb[0];
  float M = e00;
  float A = (l < CC) ? __expf(lgb[l] - e00) : 0.f;
  for (int t = 1; t < len; ++t) {
    float s0 = 0.f, s1 = 0.f, s2 = 0.f, s3 = 0.f, s4 = 0.f;
#pragma unroll
    for (int i = 0; i < CC; i += 5) {
      s0 += __shfl(A, i + 0, 64) * et[i + 0];
      s1 += __shfl(A, i + 1, 64) * et[i + 1];
      s2 += __shfl(A, i + 2, 64) * et[i + 2];
      s3 += __shfl(A, i + 3, 64) * et[i + 3];
      s4 += __shfl(A, i + 4, 64) * et[i + 4];
    }
    A = (((s0 + s1) + (s2 + s3)) + s4) * eexp[t * CC + lc];
    if ((t & 3) == 0) {
      const float r = __shfl(A, 0, 64);
      M += __logf(r);
      A *= __builtin_amdgcn_rcpf(r);
    }
  }
  const float tot = wredsum((l < CC) ? A : 0.f);
  float gold = 0.f;
  for (int t = l; t < TT; t += 64)
    if (t < len) gold += lgb[t * CC + tag[b * TT + t]];
  for (int t = 1 + l; t < TT; t += 64)
    if (t < len) gold += tr[tag[b * TT + t - 1] * CC + tag[b * TT + t]];
  gold = wredsum(gold);
  if (l == 0) nll[b] = (M + __logf(tot)) - gold;
}

__global__ __launch_bounds__(64) void final_k(const float* __restrict__ nll,
                                              float* __restrict__ out) {
  float v = nll[threadIdx.x];
  v = wredsum(v);
  if (threadIdx.x == 0) out[0] = v * (1.0f / 64.0f);
}

}  // namespace

extern "C" void kernel_launch(void* const* d_in, const int* in_sizes, int n_in,
                              void* d_out, int out_size, void* d_ws, size_t ws_size,
                              hipStream_t stream) {
  (void)in_sizes; (void)n_in; (void)out_size; (void)ws_size;
  const int* chi = (const int*)d_in[0];
  const int* wdi = (const int*)d_in[1];
  const int* psi = (const int*)d_in[2];
  const float* spo = (const float*)d_in[3];
  const int* seq_len = (const int*)d_in[4];
  const int* tag = (const int*)d_in[5];
  const float* ctab = (const float*)d_in[6];
  const float* wtab = (const float*)d_in[7];
  const float* ptab = (const float*)d_in[8];
  const float* ln0g = (const float*)d_in[9];
  const float* ln0b = (const float*)d_in[10];
  const float* Wq = (const float*)d_in[11];
  const float* bq = (const float*)d_in[12];
  const float* Wk = (const float*)d_in[13];
  const float* bk = (const float*)d_in[14];
  const float* Wv = (const float*)d_in[15];
  const float* bv = (const float*)d_in[16];
  const float* Wo = (const float*)d_in[17];
  const float* bo = (const float*)d_in[18];
  const float* ln1g = (const float*)d_in[19];
  const float* ln1b = (const float*)d_in[20];
  const float* W1 = (const float*)d_in[21];
  const float* b1 = (const float*)d_in[22];
  const float* W2 = (const float*)d_in[23];
  const float* b2 = (const float*)d_in[24];
  const float* ln2g = (const float*)d_in[25];
  const float* ln2b = (const float*)d_in[26];
  const float* Wout = (const float*)d_in[27];
  const float* bout = (const float*)d_in[28];
  const float* trans = (const float*)d_in[29];

  // ---- workspace layout (~187 MB) ----
  char* w8 = (char*)d_ws;
  float* x = (float*)(w8);                              // 32MB f32 activations
  float* t0 = (float*)(w8 + 32 * MB);                   // 32MB ffn-out f32
  unsigned short* cb = (unsigned short*)t0;             // ctx bf16 (dead before t0 write)
  float* h1f = (float*)(w8 + 64 * MB);                  // 32MB h1 f32
  unsigned short* xb = (unsigned short*)(w8 + 96 * MB); // 16MB x bf16
  unsigned short* qbuf = (unsigned short*)(w8 + 112 * MB); // 16MB q bf16 [B,H,T,DH]
  unsigned short* ib = qbuf;                            // 32MB ffn inner (qbuf+kbuf)
  unsigned short* kbuf = (unsigned short*)(w8 + 128 * MB); // 16MB k bf16 [B,H,T,DH]
  _Float16* vtb = (_Float16*)(w8 + 144 * MB);           // 16MB v^T f16 [B,H,DH,T]
  unsigned short* hb = (unsigned short*)(w8 + 144 * MB);// h1 bf16 (vtb dead post-attn)
  unsigned short* wqkv = (unsigned short*)(w8 + 160 * MB);  // [L][1536][512] 6MB
  unsigned short* wot = (unsigned short*)(w8 + 166 * MB);   // [L][512][512] 2MB
  unsigned short* w1t = (unsigned short*)(w8 + 168 * MB);   // [L][2048][512] 8MB
  unsigned short* w2t = (unsigned short*)(w8 + 176 * MB);   // [L][512][2048] 8MB
  float* lg = (float*)(w8 + 184 * MB);
  float* nll = (float*)(w8 + 186 * MB);

  const size_t QKVS = (size_t)1536 * 512;
  wconv_k<<<dim3(8, 8, LT), 256, 0, stream>>>(Wq, wqkv, DD, DD, QKVS);
  wconv_k<<<dim3(8, 8, LT), 256, 0, stream>>>(Wk, wqkv + 512 * 512, DD, DD, QKVS);
  wconv_k<<<dim3(8, 8, LT), 256, 0, stream>>>(Wv, wqkv + 1024 * 512, DD, DD, QKVS);
  wconv_k<<<dim3(8, 8, LT), 256, 0, stream>>>(Wo, wot, DD, DD, (size_t)DD * DD);
  wconv_k<<<dim3(8, 32, LT), 256, 0, stream>>>(W1, w1t, DD, FF, (size_t)DD * FF);
  wconv_k<<<dim3(32, 8, LT), 256, 0, stream>>>(W2, w2t, FF, DD, (size_t)FF * DD);

  embed_ln0_k<<<M_ALL, 64, 0, stream>>>(chi, wdi, psi, spo, ctab, wtab, ptab,
                                        ln0g, ln0b, x, xb);

  for (int l = 0; l < LT; ++l) {
    gemm_mfma<5><<<dim3(12, 128), 256, 0, stream>>>(
        xb, wqkv + (size_t)l * QKVS, bq + l * DD, bk + l * DD, bv + l * DD,
        nullptr, qbuf, kbuf, vtb, M_ALL, 1536, DD);
    attn_mfma_k<<<BB * HH, 256, 0, stream>>>(qbuf, kbuf, vtb, seq_len, cb);
    gemm_mfma<0><<<dim3(4, 128), 256, 0, stream>>>(
        cb, wot + (size_t)l * DD * DD, bo + l * DD, nullptr, nullptr, nullptr,
        h1f, nullptr, nullptr, M_ALL, DD, DD);
    ln_k<0><<<M_ALL, 64, 0, stream>>>(h1f, x, ln1g + l * DD, ln1b + l * DD,
                                      nullptr, h1f, hb);
    for (int c = 0; c < 2; ++c) {
      const size_t ro = (size_t)c * 8192 * DD;
      gemm_mfma<1><<<dim3(FF / 128, 8192 / 128), 256, 0, stream>>>(
          hb + ro, w1t + (size_t)l * FF * DD, b1 + l * FF, nullptr, nullptr,
          nullptr, ib, nullptr, nullptr, 8192, FF, DD);
      gemm_mfma<2><<<dim3(DD / 128, 8192 / 128), 256, 0, stream>>>(
          ib, w2t + (size_t)l * FF * DD, b2 + l * DD, nullptr, nullptr,
          h1f + ro, t0 + ro, nullptr, nullptr, 8192, DD, FF);
    }
    ln_k<1><<<M_ALL, 64, 0, stream>>>(t0, nullptr, ln2g + l * DD, ln2b + l * DD,
                                      seq_len, x, xb);
  }
  logits_k<<<M_ALL / 8, 256, 0, stream>>>(x, Wout, bout, lg);
  crf_k<<<BB, 64, 0, stream>>>(lg, tag, seq_len, trans, nll);
  final_k<<<1, 64, 0, stream>>>(nll, (float*)d_out);
}

// Round 5
// 1102.363 us; speedup vs baseline: 7.4729x; 1.0854x over previous
//
#include <hip/hip_runtime.h>
#include <cmath>

namespace {

constexpr int LT = 4;       // layers
constexpr int BB = 64;      // batch
constexpr int TT = 256;     // seq len
constexpr int DD = 512;     // model dim
constexpr int HH = 8;       // heads
constexpr int DH = 64;      // head dim
constexpr int FF = 2048;    // ffn inner
constexpr int CC = 25;      // tag classes
constexpr int M_ALL = BB * TT;   // 16384 token rows
constexpr size_t MB = 1024 * 1024;

typedef __attribute__((ext_vector_type(8))) short short8;
typedef __attribute__((ext_vector_type(4))) short short4_;
typedef __attribute__((ext_vector_type(4))) float f32x4;
typedef __attribute__((ext_vector_type(4))) _Float16 half4;

__device__ __forceinline__ float b2f(unsigned short u) {
  union { unsigned int i; float f; } x; x.i = ((unsigned int)u) << 16; return x.f;
}
__device__ __forceinline__ unsigned short f2b(float f) {
  union { float f; unsigned int i; } x; x.f = f;
  unsigned int r = x.i + 0x7FFFu + ((x.i >> 16) & 1u);
  return (unsigned short)(r >> 16);
}
__device__ __forceinline__ float rdlane(float v, int l) {
  union { float f; unsigned int i; } x; x.f = v;
  x.i = (unsigned int)__builtin_amdgcn_readlane((int)x.i, l);
  return x.f;
}
__device__ __forceinline__ void gl_lds16(const void* g, void* l) {
  __builtin_amdgcn_global_load_lds(
      (const __attribute__((address_space(1))) unsigned int*)g,
      (__attribute__((address_space(3))) unsigned int*)l, 16, 0, 0);
}
__device__ __forceinline__ float wredsum(float v) {
#pragma unroll
  for (int o = 32; o > 0; o >>= 1) v += __shfl_xor(v, o, 64);
  return v;
}

// ---------------- weight convert+transpose: in [K,N] f32 -> out [N,K] bf16 ---
__global__ __launch_bounds__(256) void wconv_k(const float* __restrict__ in,
                                               unsigned short* __restrict__ out,
                                               int K, int N, size_t lstride) {
  __shared__ float ts[64][65];
  const int k0 = blockIdx.x * 64, n0 = blockIdx.y * 64;
  in += (size_t)blockIdx.z * K * N;
  out += (size_t)blockIdx.z * lstride;
  const int tid = threadIdx.x;
  for (int i = tid; i < 1024; i += 256) {
    const int r = i >> 4, c4 = i & 15;
    const float4 f = *(const float4*)&in[(size_t)(k0 + r) * N + n0 + c4 * 4];
    ts[r][c4 * 4 + 0] = f.x; ts[r][c4 * 4 + 1] = f.y;
    ts[r][c4 * 4 + 2] = f.z; ts[r][c4 * 4 + 3] = f.w;
  }
  __syncthreads();
  const int n_r = tid >> 2, kc = (tid & 3) * 16;
  short8 v0, v1;
#pragma unroll
  for (int j = 0; j < 8; ++j) {
    v0[j] = (short)f2b(ts[kc + j][n_r]);
    v1[j] = (short)f2b(ts[kc + 8 + j][n_r]);
  }
  unsigned short* op = out + (size_t)(n0 + n_r) * K + k0 + kc;
  *(short8*)op = v0;
  *(short8*)(op + 8) = v1;
}

// ---------------- embed (char|word|pos|spo concat) + LN0 -> bf16 ------------
__global__ __launch_bounds__(64) void embed_ln0_k(
    const int* __restrict__ ch, const int* __restrict__ wd, const int* __restrict__ ps,
    const float* __restrict__ spo, const float* __restrict__ ctab,
    const float* __restrict__ wtab, const float* __restrict__ ptab,
    const float* __restrict__ g, const float* __restrict__ be,
    unsigned short* __restrict__ xb) {
  const int row = blockIdx.x;
  const int lane = threadIdx.x;
  const int b = row >> 8;
  const int ci = ch[row], wi = wd[row], pi = ps[row];
  float v[8];
#pragma unroll
  for (int j = 0; j < 2; ++j) {
    const int d = j * 256 + lane * 4;
    float4 f;
    if (d < 128)      f = *(const float4*)&ctab[(size_t)ci * 128 + d];
    else if (d < 428) f = *(const float4*)&wtab[(size_t)wi * 300 + (d - 128)];
    else if (d < 492) f = *(const float4*)&ptab[(size_t)pi * 64 + (d - 428)];
    else              f = *(const float4*)&spo[(size_t)b * 20 + (d - 492)];
    v[j * 4 + 0] = f.x; v[j * 4 + 1] = f.y; v[j * 4 + 2] = f.z; v[j * 4 + 3] = f.w;
  }
  float s = 0.f;
#pragma unroll
  for (int i = 0; i < 8; ++i) s += v[i];
  const float mean = wredsum(s) * (1.0f / 512.0f);
  float vs = 0.f;
#pragma unroll
  for (int i = 0; i < 8; ++i) { const float d = v[i] - mean; vs += d * d; }
  const float rstd = rsqrtf(wredsum(vs) * (1.0f / 512.0f) + 1e-5f);
#pragma unroll
  for (int j = 0; j < 2; ++j) {
    const int d = j * 256 + lane * 4;
    const float4 gv = *(const float4*)&g[d];
    const float4 bv = *(const float4*)&be[d];
    short4_ ob;
    ob[0] = (short)f2b((v[j * 4 + 0] - mean) * rstd * gv.x + bv.x);
    ob[1] = (short)f2b((v[j * 4 + 1] - mean) * rstd * gv.y + bv.y);
    ob[2] = (short)f2b((v[j * 4 + 2] - mean) * rstd * gv.z + bv.z);
    ob[3] = (short)f2b((v[j * 4 + 3] - mean) * rstd * gv.w + bv.w);
    *(short4_*)&xb[(size_t)row * DD + d] = ob;
  }
}

// ---------------- MFMA GEMM: C = A[M,K](bf16) * Bt[N,K](bf16)^T + bias -------
// EPI: 1 bf16+bias+relu; 5 fused QKV scatter; 6 bf16+bias; 7 bf16+bias+bf16 res
template <int EPI>
__global__ __launch_bounds__(256) void gemm_mfma(
    const unsigned short* __restrict__ A, const unsigned short* __restrict__ Bt,
    const float* __restrict__ bias, const float* __restrict__ bias2,
    const float* __restrict__ bias3, const unsigned short* __restrict__ res,
    void* __restrict__ outv, void* __restrict__ out2v, void* __restrict__ out3v,
    int M, int N, int K) {
  __shared__ unsigned short As[128 * 64];
  __shared__ unsigned short Bs[128 * 64];
  const int tid = threadIdx.x;
  const int m0 = blockIdx.y * 128, n0 = blockIdx.x * 128;
  const int wid = tid >> 6, lane = tid & 63;
  const int wr = wid >> 1, wc = wid & 1;
  const int cl = lane & 15, rg = lane >> 4;
  f32x4 acc[4][4];
#pragma unroll
  for (int i = 0; i < 4; ++i)
#pragma unroll
    for (int j = 0; j < 4; ++j) acc[i][j] = (f32x4){0.f, 0.f, 0.f, 0.f};

  const int rbase = tid >> 3, sl = tid & 7;
  const int sc = 8 * (sl ^ (rbase & 7));

  for (int k0 = 0; k0 < K; k0 += 64) {
    if (k0) __syncthreads();
#pragma unroll
    for (int i = 0; i < 4; ++i) {
      const int r = i * 32 + rbase;
      gl_lds16(A + (size_t)(m0 + r) * K + k0 + sc, (char*)As + (i * 256 + tid) * 16);
      gl_lds16(Bt + (size_t)(n0 + r) * K + k0 + sc, (char*)Bs + (i * 256 + tid) * 16);
    }
    __syncthreads();
#pragma unroll
    for (int ks = 0; ks < 2; ++ks) {
      short8 a[4], b[4];
      const int kbyte = ks * 64 + rg * 16;
#pragma unroll
      for (int f = 0; f < 4; ++f) {
        const int am = wr * 64 + f * 16 + cl;
        a[f] = *(const short8*)((const char*)As + am * 128 + (kbyte ^ ((am & 7) << 4)));
        const int bn = wc * 64 + f * 16 + cl;
        b[f] = *(const short8*)((const char*)Bs + bn * 128 + (kbyte ^ ((bn & 7) << 4)));
      }
#pragma unroll
      for (int mi = 0; mi < 4; ++mi)
#pragma unroll
        for (int ni = 0; ni < 4; ++ni)
          acc[mi][ni] = __builtin_amdgcn_mfma_f32_16x16x32_bf16(a[mi], b[ni],
                                                                acc[mi][ni], 0, 0, 0);
    }
  }

#pragma unroll
  for (int ni = 0; ni < 4; ++ni) {
    const int n = n0 + wc * 64 + ni * 16 + cl;
    float bv;
    if constexpr (EPI == 5) {
      bv = (n < 512) ? bias[n] : (n < 1024 ? bias2[n - 512] : bias3[n - 1024]);
    } else {
      bv = bias[n];
    }
#pragma unroll
    for (int mi = 0; mi < 4; ++mi) {
      if constexpr (EPI == 5) {
        const int mb = m0 + wr * 64 + mi * 16 + rg * 4;
        const int bb = mb >> 8, t0v = mb & 255;  // i=0..3 stays in same 256-block
        if (n < 1024) {
          const int n2 = n & 511, hh = n2 >> 6, d = n2 & 63;
          unsigned short* outp = (unsigned short*)((n < 512) ? outv : out2v);
#pragma unroll
          for (int i = 0; i < 4; ++i)
            outp[(((size_t)(bb * HH + hh) * TT + t0v + i) << 6) + d] =
                f2b(acc[mi][ni][i] + bv);
        } else {
          const int n2 = n - 1024, hh = n2 >> 6, d = n2 & 63;
          half4 pk;
#pragma unroll
          for (int i = 0; i < 4; ++i) pk[i] = (_Float16)(acc[mi][ni][i] + bv);
          *(half4*)((_Float16*)out3v + (((size_t)(bb * HH + hh) * DH + d) << 8) + t0v) = pk;
        }
      } else {
#pragma unroll
        for (int i = 0; i < 4; ++i) {
          const int m = m0 + wr * 64 + mi * 16 + rg * 4 + i;
          float v = acc[mi][ni][i] + bv;
          if constexpr (EPI == 1) {
            ((unsigned short*)outv)[(size_t)m * N + n] = f2b(fmaxf(v, 0.f));
          } else if constexpr (EPI == 6) {
            ((unsigned short*)outv)[(size_t)m * N + n] = f2b(v);
          } else if constexpr (EPI == 7) {
            ((unsigned short*)outv)[(size_t)m * N + n] =
                f2b(v + b2f(res[(size_t)m * N + n]));
          }
        }
      }
    }
  }
}

// ---------------- MFMA flash attention --------------------------------------
// qb/kb [B,H,T,DH] bf16, vt [B,H,DH,T] f16, out cb [B,T,H*DH] bf16.
__global__ __launch_bounds__(256) void attn_mfma_k(
    const unsigned short* __restrict__ qb, const unsigned short* __restrict__ kbp,
    const _Float16* __restrict__ vtp, const int* __restrict__ seq_len,
    unsigned short* __restrict__ cb) {
  __shared__ unsigned short Ks[256 * 64];  // [t][d] bf16, 16B-slot XOR swizzle
  __shared__ _Float16 Vs[64 * 256];        // [d][t] f16, swizzled
  __shared__ unsigned short Os[64 * 64];   // out transpose stage, swizzled
  const int bh = blockIdx.x;
  const int b = bh >> 3, h = bh & 7;
  const int tid = threadIdx.x;
  const int wid = tid >> 6, lane = tid & 63;
  const int cl = lane & 15, rg = lane >> 4;
  const int len = seq_len[b];

  {  // stage K (32KB) and V^T (32KB), pre-swizzled source -> linear LDS
    const int r = tid >> 3, sl = tid & 7;
#pragma unroll
    for (int i = 0; i < 8; ++i) {
      const int row = i * 32 + r;
      gl_lds16(kbp + ((size_t)bh * TT + row) * DH + 8 * (sl ^ (row & 7)),
               (char*)Ks + (i * 256 + tid) * 16);
    }
#pragma unroll
    for (int i = 0; i < 8; ++i) {
      const int u = i * 256 + tid;
      const int vrow = u >> 5, vsl = u & 31;
      gl_lds16(vtp + ((size_t)bh * DH + vrow) * TT + 8 * (vsl ^ (vrow & 7)),
               (char*)Vs + u * 16);
    }
  }
  __syncthreads();

  for (int qt4 = 0; qt4 < 4; ++qt4) {
    f32x4 o[4];
#pragma unroll
    for (int db = 0; db < 4; ++db) o[db] = (f32x4){0.f, 0.f, 0.f, 0.f};
    if (qt4 * 64 < len) {  // block-uniform
      const int q0 = qt4 * 64 + wid * 16;
      short8 bqf[2];
      const unsigned short* qp = qb + ((size_t)bh * TT + q0 + cl) * DH + rg * 8;
      bqf[0] = *(const short8*)qp;
      bqf[1] = *(const short8*)(qp + 32);
      f32x4 s[16];
#pragma unroll
      for (int kk = 0; kk < 16; ++kk) {
        s[kk] = (f32x4){0.f, 0.f, 0.f, 0.f};
        if (kk * 16 < len) {
          const int row = kk * 16 + cl;
          const char* base = (const char*)Ks + row * 128;
          const int sw = (row & 7) << 4;
          const short8 a0 = *(const short8*)(base + ((rg * 16) ^ sw));
          const short8 a1 = *(const short8*)(base + ((64 + rg * 16) ^ sw));
          s[kk] = __builtin_amdgcn_mfma_f32_16x16x32_bf16(a0, bqf[0], s[kk], 0, 0, 0);
          s[kk] = __builtin_amdgcn_mfma_f32_16x16x32_bf16(a1, bqf[1], s[kk], 0, 0, 0);
        }
      }
      float mx = -3.0e38f;
#pragma unroll
      for (int kk = 0; kk < 16; ++kk)
        if (kk * 16 < len) {
#pragma unroll
          for (int i = 0; i < 4; ++i) {
            float v = s[kk][i] * 0.125f;
            v = (kk * 16 + rg * 4 + i < len) ? v : -3.0e38f;
            s[kk][i] = v;
            mx = fmaxf(mx, v);
          }
        }
      mx = fmaxf(mx, __shfl_xor(mx, 16, 64));
      mx = fmaxf(mx, __shfl_xor(mx, 32, 64));
      float lsum = 0.f;
#pragma unroll
      for (int kk = 0; kk < 16; ++kk)
        if (kk * 16 < len) {
#pragma unroll
          for (int i = 0; i < 4; ++i) {
            const float p = __expf(s[kk][i] - mx);
            s[kk][i] = p;
            lsum += p;
          }
        }
      lsum += __shfl_xor(lsum, 16, 64);
      lsum += __shfl_xor(lsum, 32, 64);
      const float rl = 1.0f / lsum;
#pragma unroll
      for (int kk = 0; kk < 16; ++kk)
        if (kk * 16 < len) {
          half4 bp;
#pragma unroll
          for (int i = 0; i < 4; ++i) bp[i] = (_Float16)(s[kk][i] * rl);
#pragma unroll
          for (int db = 0; db < 4; ++db) {
            const int vrow = db * 16 + cl;
            const int byte = kk * 32 + rg * 8;
            const half4 a = *(const half4*)((const char*)Vs + vrow * 512 +
                              ((byte & ~15) ^ ((vrow & 7) << 4)) + (byte & 15));
            o[db] = __builtin_amdgcn_mfma_f32_16x16x16f16(a, bp, o[db], 0, 0, 0);
          }
        }
    }
    __syncthreads();
    {
      const int orow = wid * 16 + cl;
      char* obase = (char*)Os + orow * 128;
      const int sw = (orow & 7) << 4;
#pragma unroll
      for (int db = 0; db < 4; ++db) {
        short4_ pk;
#pragma unroll
        for (int i = 0; i < 4; ++i) pk[i] = (short)f2b(o[db][i]);
        const int byte = db * 32 + rg * 8;
        *(short4_*)(obase + ((byte & ~15) ^ sw) + (byte & 15)) = pk;
      }
    }
    __syncthreads();
    {  // coalesced copy Os (64q x 64d bf16) -> cb
      const int r = tid >> 2, part = tid & 3;
      const int sw = (r & 7) << 4;
      const char* rbase = (const char*)Os + r * 128;
      const short8 w0 = *(const short8*)(rbase + ((part * 32) ^ sw));
      const short8 w1 = *(const short8*)(rbase + ((part * 32 + 16) ^ sw));
      unsigned short* dst = cb + ((size_t)(b * TT + qt4 * 64 + r)) * DD + h * DH + part * 16;
      *(short8*)dst = w0;
      *(short8*)(dst + 8) = w1;
    }
  }
}

// ---------------- row LayerNorm, bf16 in/out --------------------------------
// MODE 0: out=LN(a+b2); MODE 1: out=LN(a)*mask
template <int MODE>
__global__ __launch_bounds__(64) void ln_k(const unsigned short* __restrict__ a,
                                           const unsigned short* __restrict__ b2,
                                           const float* __restrict__ g,
                                           const float* __restrict__ be,
                                           const int* __restrict__ seq_len,
                                           unsigned short* __restrict__ outb) {
  const int row = blockIdx.x, lane = threadIdx.x;
  float v[8];
  {
    const short8 va = *(const short8*)&a[(size_t)row * DD + lane * 8];
    if constexpr (MODE == 0) {
      const short8 vb = *(const short8*)&b2[(size_t)row * DD + lane * 8];
#pragma unroll
      for (int i = 0; i < 8; ++i)
        v[i] = b2f((unsigned short)va[i]) + b2f((unsigned short)vb[i]);
    } else {
#pragma unroll
      for (int i = 0; i < 8; ++i) v[i] = b2f((unsigned short)va[i]);
    }
  }
  float s = 0.f;
#pragma unroll
  for (int i = 0; i < 8; ++i) s += v[i];
  const float mean = wredsum(s) * (1.0f / 512.0f);
  float vs = 0.f;
#pragma unroll
  for (int i = 0; i < 8; ++i) { const float d = v[i] - mean; vs += d * d; }
  const float rstd = rsqrtf(wredsum(vs) * (1.0f / 512.0f) + 1e-5f);
  float msk = 1.0f;
  if constexpr (MODE == 1) msk = ((row & 255) < seq_len[row >> 8]) ? 1.0f : 0.0f;
  const float4 g0 = *(const float4*)&g[lane * 8];
  const float4 g1 = *(const float4*)&g[lane * 8 + 4];
  const float4 b0 = *(const float4*)&be[lane * 8];
  const float4 b1 = *(const float4*)&be[lane * 8 + 4];
  const float gg[8] = {g0.x, g0.y, g0.z, g0.w, g1.x, g1.y, g1.z, g1.w};
  const float bb[8] = {b0.x, b0.y, b0.z, b0.w, b1.x, b1.y, b1.z, b1.w};
  short8 ob;
#pragma unroll
  for (int i = 0; i < 8; ++i)
    ob[i] = (short)f2b(((v[i] - mean) * rstd * gg[i] + bb[i]) * msk);
  *(short8*)&outb[(size_t)row * DD + lane * 8] = ob;
}

// ---------------- logits = x(bf16) @ Wout + bout,  N=25 ---------------------
__global__ __launch_bounds__(256) void logits_k(const unsigned short* __restrict__ xb,
                                                const float* __restrict__ W,
                                                const float* __restrict__ bo,
                                                float* __restrict__ lg) {
  __shared__ float xs[8][516];
  const int r0 = blockIdx.x * 8;
  for (int i = threadIdx.x; i < 512; i += 256) {
    const int rr = i >> 6, c8 = (i & 63) * 8;
    const short8 v = *(const short8*)&xb[(size_t)(r0 + rr) * DD + c8];
#pragma unroll
    for (int j = 0; j < 8; ++j) xs[rr][c8 + j] = b2f((unsigned short)v[j]);
  }
  __syncthreads();
  const int r = threadIdx.x >> 5, c = threadIdx.x & 31;
  if (c < CC) {
    float acc = 0.f;
#pragma unroll 8
    for (int k = 0; k < DD; ++k) acc += xs[r][k] * W[k * CC + c];
    lg[(size_t)(r0 + r) * CC + c] = acc + bo[c];
  }
}

// ---------------- CRF: linear-domain scan via v_readlane --------------------
// A_j = exp(alpha_j - M); step: A'_j = (sum_i A_i e^trans[i][j]) e^emit[t][j].
// readlane (VALU, no LDS latency) replaces ds_bpermute broadcasts.
__global__ __launch_bounds__(64) void crf_k(const float* __restrict__ lg,
                                            const int* __restrict__ tag,
                                            const int* __restrict__ seq_len,
                                            const float* __restrict__ trans,
                                            float* __restrict__ nll) {
  __shared__ float eexp[TT * CC + 64];
  __shared__ float tr[CC * CC];
  const int b = blockIdx.x;
  const int l = threadIdx.x;
  const float* lgb = lg + (size_t)b * TT * CC;
  for (int i = l; i < TT * CC; i += 64) eexp[i] = __expf(lgb[i]);
  for (int i = l; i < CC * CC; i += 64) tr[i] = trans[i];
  __syncthreads();
  const int len = seq_len[b];
  const int lc = (l < CC) ? l : (CC - 1);
  float et[CC];
#pragma unroll
  for (int i = 0; i < CC; ++i) et[i] = __expf(tr[i * CC + lc]);
  const float e00 = lgb[0];
  float M = e00;
  float A = (l < CC) ? __expf(lgb[l] - e00) : 0.f;
  for (int t = 1; t < len; ++t) {
    const float e = eexp[t * CC + lc];
    float s0 = 0.f, s1 = 0.f, s2 = 0.f, s3 = 0.f, s4 = 0.f;
#pragma unroll
    for (int i = 0; i < CC; i += 5) {
      s0 += rdlane(A, i + 0) * et[i + 0];
      s1 += rdlane(A, i + 1) * et[i + 1];
      s2 += rdlane(A, i + 2) * et[i + 2];
      s3 += rdlane(A, i + 3) * et[i + 3];
      s4 += rdlane(A, i + 4) * et[i + 4];
    }
    A = (((s0 + s1) + (s2 + s3)) + s4) * e;
    if ((t & 3) == 0) {
      const float r = rdlane(A, 0);  // A_0 > 0 always (dense transitions)
      M += __logf(r);
      A *= __builtin_amdgcn_rcpf(r);
    }
  }
  const float tot = wredsum((l < CC) ? A : 0.f);
  float gold = 0.f;
  for (int t = l; t < TT; t += 64)
    if (t < len) gold += lgb[t * CC + tag[b * TT + t]];
  for (int t = 1 + l; t < TT; t += 64)
    if (t < len) gold += tr[tag[b * TT + t - 1] * CC + tag[b * TT + t]];
  gold = wredsum(gold);
  if (l == 0) nll[b] = (M + __logf(tot)) - gold;
}

__global__ __launch_bounds__(64) void final_k(const float* __restrict__ nll,
                                              float* __restrict__ out) {
  float v = nll[threadIdx.x];
  v = wredsum(v);
  if (threadIdx.x == 0) out[0] = v * (1.0f / 64.0f);
}

}  // namespace

extern "C" void kernel_launch(void* const* d_in, const int* in_sizes, int n_in,
                              void* d_out, int out_size, void* d_ws, size_t ws_size,
                              hipStream_t stream) {
  (void)in_sizes; (void)n_in; (void)out_size; (void)ws_size;
  const int* chi = (const int*)d_in[0];
  const int* wdi = (const int*)d_in[1];
  const int* psi = (const int*)d_in[2];
  const float* spo = (const float*)d_in[3];
  const int* seq_len = (const int*)d_in[4];
  const int* tag = (const int*)d_in[5];
  const float* ctab = (const float*)d_in[6];
  const float* wtab = (const float*)d_in[7];
  const float* ptab = (const float*)d_in[8];
  const float* ln0g = (const float*)d_in[9];
  const float* ln0b = (const float*)d_in[10];
  const float* Wq = (const float*)d_in[11];
  const float* bq = (const float*)d_in[12];
  const float* Wk = (const float*)d_in[13];
  const float* bk = (const float*)d_in[14];
  const float* Wv = (const float*)d_in[15];
  const float* bv = (const float*)d_in[16];
  const float* Wo = (const float*)d_in[17];
  const float* bo = (const float*)d_in[18];
  const float* ln1g = (const float*)d_in[19];
  const float* ln1b = (const float*)d_in[20];
  const float* W1 = (const float*)d_in[21];
  const float* b1 = (const float*)d_in[22];
  const float* W2 = (const float*)d_in[23];
  const float* b2 = (const float*)d_in[24];
  const float* ln2g = (const float*)d_in[25];
  const float* ln2b = (const float*)d_in[26];
  const float* Wout = (const float*)d_in[27];
  const float* bout = (const float*)d_in[28];
  const float* trans = (const float*)d_in[29];

  // ---- workspace layout (~187 MB), all buffers disjoint ----
  char* w8 = (char*)d_ws;
  unsigned short* ib  = (unsigned short*)(w8);            // 32MB ffn inner chunk [8192][2048]
  unsigned short* t0b = (unsigned short*)(w8 + 32 * MB);  // 16MB ffn-out bf16
  unsigned short* ab  = (unsigned short*)(w8 + 48 * MB);  // 16MB att_out bf16
  unsigned short* hb  = (unsigned short*)(w8 + 64 * MB);  // 16MB h1 bf16
  unsigned short* cbx = (unsigned short*)(w8 + 80 * MB);  // 16MB ctx bf16
  unsigned short* xb  = (unsigned short*)(w8 + 96 * MB);  // 16MB x bf16
  unsigned short* qbuf = (unsigned short*)(w8 + 112 * MB);// 16MB q bf16 [B,H,T,DH]
  unsigned short* kbuf = (unsigned short*)(w8 + 128 * MB);// 16MB k bf16 [B,H,T,DH]
  _Float16* vtb = (_Float16*)(w8 + 144 * MB);             // 16MB v^T f16 [B,H,DH,T]
  unsigned short* wqkv = (unsigned short*)(w8 + 160 * MB);// [L][1536][512] 6MB
  unsigned short* wot = (unsigned short*)(w8 + 166 * MB); // [L][512][512] 2MB
  unsigned short* w1t = (unsigned short*)(w8 + 168 * MB); // [L][2048][512] 8MB
  unsigned short* w2t = (unsigned short*)(w8 + 176 * MB); // [L][512][2048] 8MB
  float* lg = (float*)(w8 + 184 * MB);
  float* nll = (float*)(w8 + 186 * MB);

  const size_t QKVS = (size_t)1536 * 512;
  wconv_k<<<dim3(8, 8, LT), 256, 0, stream>>>(Wq, wqkv, DD, DD, QKVS);
  wconv_k<<<dim3(8, 8, LT), 256, 0, stream>>>(Wk, wqkv + 512 * 512, DD, DD, QKVS);
  wconv_k<<<dim3(8, 8, LT), 256, 0, stream>>>(Wv, wqkv + 1024 * 512, DD, DD, QKVS);
  wconv_k<<<dim3(8, 8, LT), 256, 0, stream>>>(Wo, wot, DD, DD, (size_t)DD * DD);
  wconv_k<<<dim3(8, 32, LT), 256, 0, stream>>>(W1, w1t, DD, FF, (size_t)DD * FF);
  wconv_k<<<dim3(32, 8, LT), 256, 0, stream>>>(W2, w2t, FF, DD, (size_t)FF * DD);

  embed_ln0_k<<<M_ALL, 64, 0, stream>>>(chi, wdi, psi, spo, ctab, wtab, ptab,
                                        ln0g, ln0b, xb);

  for (int l = 0; l < LT; ++l) {
    gemm_mfma<5><<<dim3(12, 128), 256, 0, stream>>>(
        xb, wqkv + (size_t)l * QKVS, bq + l * DD, bk + l * DD, bv + l * DD,
        nullptr, qbuf, kbuf, vtb, M_ALL, 1536, DD);
    attn_mfma_k<<<BB * HH, 256, 0, stream>>>(qbuf, kbuf, vtb, seq_len, cbx);
    gemm_mfma<6><<<dim3(4, 128), 256, 0, stream>>>(
        cbx, wot + (size_t)l * DD * DD, bo + l * DD, nullptr, nullptr, nullptr,
        ab, nullptr, nullptr, M_ALL, DD, DD);
    ln_k<0><<<M_ALL, 64, 0, stream>>>(ab, xb, ln1g + l * DD, ln1b + l * DD,
                                      nullptr, hb);
    for (int c = 0; c < 2; ++c) {
      const size_t ro = (size_t)c * 8192 * DD;
      gemm_mfma<1><<<dim3(FF / 128, 8192 / 128), 256, 0, stream>>>(
          hb + ro, w1t + (size_t)l * FF * DD, b1 + l * FF, nullptr, nullptr,
          nullptr, ib, nullptr, nullptr, 8192, FF, DD);
      gemm_mfma<7><<<dim3(DD / 128, 8192 / 128), 256, 0, stream>>>(
          ib, w2t + (size_t)l * FF * DD, b2 + l * DD, nullptr, nullptr,
          hb + ro, t0b + ro, nullptr, nullptr, 8192, DD, FF);
    }
    ln_k<1><<<M_ALL, 64, 0, stream>>>(t0b, nullptr, ln2g + l * DD, ln2b + l * DD,
                                      seq_len, xb);
  }
  logits_k<<<M_ALL / 8, 256, 0, stream>>>(xb, Wout, bout, lg);
  crf_k<<<BB, 64, 0, stream>>>(lg, tag, seq_len, trans, nll);
  final_k<<<1, 64, 0, stream>>>(nll, (float*)d_out);
}

// Round 6
// 821.251 us; speedup vs baseline: 10.0308x; 1.3423x over previous
//
#include <hip/hip_runtime.h>
#include <cmath>

namespace {

constexpr int LT = 4;       // layers
constexpr int BB = 64;      // batch
constexpr int TT = 256;     // seq len
constexpr int DD = 512;     // model dim
constexpr int HH = 8;       // heads
constexpr int DH = 64;      // head dim
constexpr int FF = 2048;    // ffn inner
constexpr int CC = 25;      // tag classes
constexpr int M_ALL = BB * TT;   // 16384 padded token rows
constexpr size_t MB = 1024 * 1024;

typedef __attribute__((ext_vector_type(8))) short short8;
typedef __attribute__((ext_vector_type(4))) short short4_;
typedef __attribute__((ext_vector_type(4))) float f32x4;
typedef __attribute__((ext_vector_type(4))) _Float16 half4;

__device__ __forceinline__ float b2f(unsigned short u) {
  union { unsigned int i; float f; } x; x.i = ((unsigned int)u) << 16; return x.f;
}
__device__ __forceinline__ unsigned short f2b(float f) {
  union { float f; unsigned int i; } x; x.f = f;
  unsigned int r = x.i + 0x7FFFu + ((x.i >> 16) & 1u);
  return (unsigned short)(r >> 16);
}
__device__ __forceinline__ float rdlane(float v, int l) {
  union { float f; unsigned int i; } x; x.f = v;
  x.i = (unsigned int)__builtin_amdgcn_readlane((int)x.i, l);
  return x.f;
}
__device__ __forceinline__ void gl_lds16(const void* g, void* l) {
  __builtin_amdgcn_global_load_lds(
      (const __attribute__((address_space(1))) unsigned int*)g,
      (__attribute__((address_space(3))) unsigned int*)l, 16, 0, 0);
}
__device__ __forceinline__ float wredsum(float v) {
#pragma unroll
  for (int o = 32; o > 0; o >>= 1) v += __shfl_xor(v, o, 64);
  return v;
}

// ---------------- token compaction: boff prefix + rowmap --------------------
__global__ __launch_bounds__(64) void prefix_k(const int* __restrict__ sl,
                                               int* __restrict__ boff) {
  const int l = threadIdx.x;
  int s = sl[l];
#pragma unroll
  for (int o = 1; o < 64; o <<= 1) {
    const int u = __shfl_up(s, o, 64);
    if (l >= o) s += u;
  }
  boff[l + 1] = s;          // boff[64] == M' (valid row count)
  if (l == 0) boff[0] = 0;
}

__global__ __launch_bounds__(256) void rowmap_k(const int* __restrict__ sl,
                                                const int* __restrict__ boff,
                                                int* __restrict__ rowmap) {
  const int b = blockIdx.x, t = threadIdx.x;
  if (t < sl[b]) rowmap[boff[b] + t] = (b << 8) | t;
}

// ---------------- weight convert+transpose: [K,N] f32 -> [N,K] bf16 ---------
__global__ __launch_bounds__(256) void wconv_k(const float* __restrict__ in,
                                               unsigned short* __restrict__ out,
                                               int K, int N, size_t lstride) {
  __shared__ float ts[64][65];
  const int k0 = blockIdx.x * 64, n0 = blockIdx.y * 64;
  in += (size_t)blockIdx.z * K * N;
  out += (size_t)blockIdx.z * lstride;
  const int tid = threadIdx.x;
  for (int i = tid; i < 1024; i += 256) {
    const int r = i >> 4, c4 = i & 15;
    const float4 f = *(const float4*)&in[(size_t)(k0 + r) * N + n0 + c4 * 4];
    ts[r][c4 * 4 + 0] = f.x; ts[r][c4 * 4 + 1] = f.y;
    ts[r][c4 * 4 + 2] = f.z; ts[r][c4 * 4 + 3] = f.w;
  }
  __syncthreads();
  const int n_r = tid >> 2, kc = (tid & 3) * 16;
  short8 v0, v1;
#pragma unroll
  for (int j = 0; j < 8; ++j) {
    v0[j] = (short)f2b(ts[kc + j][n_r]);
    v1[j] = (short)f2b(ts[kc + 8 + j][n_r]);
  }
  unsigned short* op = out + (size_t)(n0 + n_r) * K + k0 + kc;
  *(short8*)op = v0;
  *(short8*)(op + 8) = v1;
}

// ---------------- embed + LN0 -> compacted bf16 -----------------------------
__global__ __launch_bounds__(64) void embed_ln0_k(
    const int* __restrict__ ch, const int* __restrict__ wd, const int* __restrict__ ps,
    const float* __restrict__ spo, const float* __restrict__ ctab,
    const float* __restrict__ wtab, const float* __restrict__ ptab,
    const float* __restrict__ g, const float* __restrict__ be,
    const int* __restrict__ sl, const int* __restrict__ boff,
    unsigned short* __restrict__ xc) {
  const int row = blockIdx.x;
  const int b = row >> 8, t = row & 255;
  if (t >= sl[b]) return;            // dead token
  const int orow = boff[b] + t;
  const int lane = threadIdx.x;
  const int ci = ch[row], wi = wd[row], pi = ps[row];
  float v[8];
#pragma unroll
  for (int j = 0; j < 2; ++j) {
    const int d = j * 256 + lane * 4;
    float4 f;
    if (d < 128)      f = *(const float4*)&ctab[(size_t)ci * 128 + d];
    else if (d < 428) f = *(const float4*)&wtab[(size_t)wi * 300 + (d - 128)];
    else if (d < 492) f = *(const float4*)&ptab[(size_t)pi * 64 + (d - 428)];
    else              f = *(const float4*)&spo[(size_t)b * 20 + (d - 492)];
    v[j * 4 + 0] = f.x; v[j * 4 + 1] = f.y; v[j * 4 + 2] = f.z; v[j * 4 + 3] = f.w;
  }
  float s = 0.f;
#pragma unroll
  for (int i = 0; i < 8; ++i) s += v[i];
  const float mean = wredsum(s) * (1.0f / 512.0f);
  float vs = 0.f;
#pragma unroll
  for (int i = 0; i < 8; ++i) { const float d = v[i] - mean; vs += d * d; }
  const float rstd = rsqrtf(wredsum(vs) * (1.0f / 512.0f) + 1e-5f);
#pragma unroll
  for (int j = 0; j < 2; ++j) {
    const int d = j * 256 + lane * 4;
    const float4 gv = *(const float4*)&g[d];
    const float4 bv = *(const float4*)&be[d];
    short4_ ob;
    ob[0] = (short)f2b((v[j * 4 + 0] - mean) * rstd * gv.x + bv.x);
    ob[1] = (short)f2b((v[j * 4 + 1] - mean) * rstd * gv.y + bv.y);
    ob[2] = (short)f2b((v[j * 4 + 2] - mean) * rstd * gv.z + bv.z);
    ob[3] = (short)f2b((v[j * 4 + 3] - mean) * rstd * gv.w + bv.w);
    *(short4_*)&xc[(size_t)orow * DD + d] = ob;
  }
}

// ---------------- MFMA GEMM on compacted rows -------------------------------
// EPI: 1 bf16+bias+relu; 5 fused QKV scatter via rowmap; 7 bf16+bias+bf16 res
template <int EPI>
__global__ __launch_bounds__(256) void gemm_mfma(
    const unsigned short* __restrict__ A, const unsigned short* __restrict__ Bt,
    const float* __restrict__ bias, const float* __restrict__ bias2,
    const float* __restrict__ bias3, const unsigned short* __restrict__ res,
    const int* __restrict__ Mptr, const int* __restrict__ rowmap,
    void* __restrict__ outv, void* __restrict__ out2v, void* __restrict__ out3v,
    int M, int N, int K) {
  const int Mp = Mptr[0];
  const int m0 = blockIdx.y * 128, n0 = blockIdx.x * 128;
  if (m0 >= Mp) return;  // block-uniform exit (whole tile dead)
  __shared__ unsigned short As[128 * 64];
  __shared__ unsigned short Bs[128 * 64];
  const int tid = threadIdx.x;
  const int wid = tid >> 6, lane = tid & 63;
  const int wr = wid >> 1, wc = wid & 1;
  const int cl = lane & 15, rg = lane >> 4;
  f32x4 acc[4][4];
#pragma unroll
  for (int i = 0; i < 4; ++i)
#pragma unroll
    for (int j = 0; j < 4; ++j) acc[i][j] = (f32x4){0.f, 0.f, 0.f, 0.f};

  const int rbase = tid >> 3, sl = tid & 7;
  const int sc = 8 * (sl ^ (rbase & 7));

  for (int k0 = 0; k0 < K; k0 += 64) {
    if (k0) __syncthreads();
#pragma unroll
    for (int i = 0; i < 4; ++i) {
      const int r = i * 32 + rbase;
      gl_lds16(A + (size_t)(m0 + r) * K + k0 + sc, (char*)As + (i * 256 + tid) * 16);
      gl_lds16(Bt + (size_t)(n0 + r) * K + k0 + sc, (char*)Bs + (i * 256 + tid) * 16);
    }
    __syncthreads();
#pragma unroll
    for (int ks = 0; ks < 2; ++ks) {
      short8 a[4], b[4];
      const int kbyte = ks * 64 + rg * 16;
#pragma unroll
      for (int f = 0; f < 4; ++f) {
        const int am = wr * 64 + f * 16 + cl;
        a[f] = *(const short8*)((const char*)As + am * 128 + (kbyte ^ ((am & 7) << 4)));
        const int bn = wc * 64 + f * 16 + cl;
        b[f] = *(const short8*)((const char*)Bs + bn * 128 + (kbyte ^ ((bn & 7) << 4)));
      }
#pragma unroll
      for (int mi = 0; mi < 4; ++mi)
#pragma unroll
        for (int ni = 0; ni < 4; ++ni)
          acc[mi][ni] = __builtin_amdgcn_mfma_f32_16x16x32_bf16(a[mi], b[ni],
                                                                acc[mi][ni], 0, 0, 0);
    }
  }

  int rm[4][4];
  if constexpr (EPI == 5) {
#pragma unroll
    for (int mi = 0; mi < 4; ++mi) {
      const int mb_ = m0 + wr * 64 + mi * 16 + rg * 4;
#pragma unroll
      for (int i = 0; i < 4; ++i)
        rm[mi][i] = (mb_ + i < Mp) ? rowmap[mb_ + i] : -1;
    }
  }

#pragma unroll
  for (int ni = 0; ni < 4; ++ni) {
    const int n = n0 + wc * 64 + ni * 16 + cl;
    float bv;
    if constexpr (EPI == 5) {
      bv = (n < 512) ? bias[n] : (n < 1024 ? bias2[n - 512] : bias3[n - 1024]);
    } else {
      bv = bias[n];
    }
#pragma unroll
    for (int mi = 0; mi < 4; ++mi) {
      if constexpr (EPI == 5) {
        const int hh = (n >> 6) & 7, d = n & 63;
        if (n < 1024) {        // q or k scatter [B,H,T,DH] bf16
          unsigned short* outp = (unsigned short*)((n < 512) ? outv : out2v);
#pragma unroll
          for (int i = 0; i < 4; ++i) {
            const int rmv = rm[mi][i];
            if (rmv >= 0) {
              const int bb = rmv >> 8, tt = rmv & 255;
              outp[(((size_t)(bb * HH + hh) * TT + tt) << 6) + d] =
                  f2b(acc[mi][ni][i] + bv);
            }
          }
        } else {               // v scatter [B,H,DH,T] f16
          const int rm0 = rm[mi][0];
          if (rm0 >= 0 && rm[mi][3] == rm0 + 3) {   // contiguous, same b
            half4 pk;
#pragma unroll
            for (int i = 0; i < 4; ++i) pk[i] = (_Float16)(acc[mi][ni][i] + bv);
            *(half4*)((_Float16*)out3v +
                      ((((size_t)((rm0 >> 8) * HH + hh) * DH + d) << 8) + (rm0 & 255))) = pk;
          } else {
#pragma unroll
            for (int i = 0; i < 4; ++i) {
              const int rmv = rm[mi][i];
              if (rmv >= 0)
                ((_Float16*)out3v)[(((size_t)((rmv >> 8) * HH + hh) * DH + d) << 8) +
                                   (rmv & 255)] = (_Float16)(acc[mi][ni][i] + bv);
            }
          }
        }
      } else {
#pragma unroll
        for (int i = 0; i < 4; ++i) {
          const int m = m0 + wr * 64 + mi * 16 + rg * 4 + i;
          const float v = acc[mi][ni][i] + bv;
          if constexpr (EPI == 1) {
            ((unsigned short*)outv)[(size_t)m * N + n] = f2b(fmaxf(v, 0.f));
          } else if constexpr (EPI == 7) {
            ((unsigned short*)outv)[(size_t)m * N + n] =
                f2b(v + b2f(res[(size_t)m * N + n]));
          }
        }
      }
    }
  }
}

// ---------------- MFMA flash attention (compacted ctx out) ------------------
__global__ __launch_bounds__(256) void attn_mfma_k(
    const unsigned short* __restrict__ qb, const unsigned short* __restrict__ kbp,
    const _Float16* __restrict__ vtp, const int* __restrict__ seq_len,
    const int* __restrict__ boff, unsigned short* __restrict__ cb) {
  __shared__ unsigned short Ks[256 * 64];  // [t][d] bf16, 16B-slot XOR swizzle
  __shared__ _Float16 Vs[64 * 256];        // [d][t] f16, swizzled
  __shared__ unsigned short Os[64 * 64];   // out transpose stage, swizzled
  const int bh = blockIdx.x;
  const int b = bh >> 3, h = bh & 7;
  const int tid = threadIdx.x;
  const int wid = tid >> 6, lane = tid & 63;
  const int cl = lane & 15, rg = lane >> 4;
  const int len = seq_len[b];
  const int off = boff[b];

  {  // stage K (len-bounded) and full V^T
    const int r = tid >> 3, sl = tid & 7;
#pragma unroll
    for (int i = 0; i < 8; ++i) {
      if (i * 32 < len) {   // block-uniform skip of dead K rows
        const int row = i * 32 + r;
        gl_lds16(kbp + ((size_t)bh * TT + row) * DH + 8 * (sl ^ (row & 7)),
                 (char*)Ks + (i * 256 + tid) * 16);
      }
    }
#pragma unroll
    for (int i = 0; i < 8; ++i) {
      const int u = i * 256 + tid;
      const int vrow = u >> 5, vsl = u & 31;
      gl_lds16(vtp + ((size_t)bh * DH + vrow) * TT + 8 * (vsl ^ (vrow & 7)),
               (char*)Vs + u * 16);
    }
  }
  __syncthreads();

  for (int qt4 = 0; qt4 < 4; ++qt4) {
    if (qt4 * 64 >= len) break;  // block-uniform
    f32x4 o[4];
#pragma unroll
    for (int db = 0; db < 4; ++db) o[db] = (f32x4){0.f, 0.f, 0.f, 0.f};
    {
      const int q0 = qt4 * 64 + wid * 16;
      short8 bqf[2];
      const unsigned short* qp = qb + ((size_t)bh * TT + q0 + cl) * DH + rg * 8;
      bqf[0] = *(const short8*)qp;
      bqf[1] = *(const short8*)(qp + 32);
      f32x4 s[16];
#pragma unroll
      for (int kk = 0; kk < 16; ++kk) {
        s[kk] = (f32x4){0.f, 0.f, 0.f, 0.f};
        if (kk * 16 < len) {
          const int row = kk * 16 + cl;
          const char* base = (const char*)Ks + row * 128;
          const int sw = (row & 7) << 4;
          const short8 a0 = *(const short8*)(base + ((rg * 16) ^ sw));
          const short8 a1 = *(const short8*)(base + ((64 + rg * 16) ^ sw));
          s[kk] = __builtin_amdgcn_mfma_f32_16x16x32_bf16(a0, bqf[0], s[kk], 0, 0, 0);
          s[kk] = __builtin_amdgcn_mfma_f32_16x16x32_bf16(a1, bqf[1], s[kk], 0, 0, 0);
        }
      }
      float mx = -3.0e38f;
#pragma unroll
      for (int kk = 0; kk < 16; ++kk)
        if (kk * 16 < len) {
#pragma unroll
          for (int i = 0; i < 4; ++i) {
            float v = s[kk][i] * 0.125f;
            v = (kk * 16 + rg * 4 + i < len) ? v : -3.0e38f;
            s[kk][i] = v;
            mx = fmaxf(mx, v);
          }
        }
      mx = fmaxf(mx, __shfl_xor(mx, 16, 64));
      mx = fmaxf(mx, __shfl_xor(mx, 32, 64));
      float lsum = 0.f;
#pragma unroll
      for (int kk = 0; kk < 16; ++kk)
        if (kk * 16 < len) {
#pragma unroll
          for (int i = 0; i < 4; ++i) {
            const float p = __expf(s[kk][i] - mx);
            s[kk][i] = p;
            lsum += p;
          }
        }
      lsum += __shfl_xor(lsum, 16, 64);
      lsum += __shfl_xor(lsum, 32, 64);
      const float rl = 1.0f / lsum;
#pragma unroll
      for (int kk = 0; kk < 16; ++kk)
        if (kk * 16 < len) {
          half4 bp;
#pragma unroll
          for (int i = 0; i < 4; ++i) bp[i] = (_Float16)(s[kk][i] * rl);
#pragma unroll
          for (int db = 0; db < 4; ++db) {
            const int vrow = db * 16 + cl;
            const int byte = kk * 32 + rg * 8;
            const half4 a = *(const half4*)((const char*)Vs + vrow * 512 +
                              ((byte & ~15) ^ ((vrow & 7) << 4)) + (byte & 15));
            o[db] = __builtin_amdgcn_mfma_f32_16x16x16f16(a, bp, o[db], 0, 0, 0);
          }
        }
    }
    __syncthreads();
    {
      const int orow = wid * 16 + cl;
      char* obase = (char*)Os + orow * 128;
      const int sw = (orow & 7) << 4;
#pragma unroll
      for (int db = 0; db < 4; ++db) {
        short4_ pk;
#pragma unroll
        for (int i = 0; i < 4; ++i) pk[i] = (short)f2b(o[db][i]);
        const int byte = db * 32 + rg * 8;
        *(short4_*)(obase + ((byte & ~15) ^ sw) + (byte & 15)) = pk;
      }
    }
    __syncthreads();
    {  // coalesced copy Os -> compacted cb, rows t < len only
      const int r = tid >> 2, part = tid & 3;
      const int t = qt4 * 64 + r;
      if (t < len) {
        const int sw = (r & 7) << 4;
        const char* rbase = (const char*)Os + r * 128;
        const short8 w0 = *(const short8*)(rbase + ((part * 32) ^ sw));
        const short8 w1 = *(const short8*)(rbase + ((part * 32 + 16) ^ sw));
        unsigned short* dst = cb + ((size_t)(off + t)) * DD + h * DH + part * 16;
        *(short8*)dst = w0;
        *(short8*)(dst + 8) = w1;
      }
    }
  }
}

// ---------------- row LayerNorm (single input, compacted) -------------------
__global__ __launch_bounds__(64) void ln_k(const unsigned short* __restrict__ a,
                                           const float* __restrict__ g,
                                           const float* __restrict__ be,
                                           const int* __restrict__ Mptr,
                                           unsigned short* __restrict__ outb) {
  const int row = blockIdx.x;
  if (row >= Mptr[0]) return;
  const int lane = threadIdx.x;
  float v[8];
  {
    const short8 va = *(const short8*)&a[(size_t)row * DD + lane * 8];
#pragma unroll
    for (int i = 0; i < 8; ++i) v[i] = b2f((unsigned short)va[i]);
  }
  float s = 0.f;
#pragma unroll
  for (int i = 0; i < 8; ++i) s += v[i];
  const float mean = wredsum(s) * (1.0f / 512.0f);
  float vs = 0.f;
#pragma unroll
  for (int i = 0; i < 8; ++i) { const float d = v[i] - mean; vs += d * d; }
  const float rstd = rsqrtf(wredsum(vs) * (1.0f / 512.0f) + 1e-5f);
  const float4 g0 = *(const float4*)&g[lane * 8];
  const float4 g1 = *(const float4*)&g[lane * 8 + 4];
  const float4 b0 = *(const float4*)&be[lane * 8];
  const float4 b1 = *(const float4*)&be[lane * 8 + 4];
  const float gg[8] = {g0.x, g0.y, g0.z, g0.w, g1.x, g1.y, g1.z, g1.w};
  const float bb[8] = {b0.x, b0.y, b0.z, b0.w, b1.x, b1.y, b1.z, b1.w};
  short8 ob;
#pragma unroll
  for (int i = 0; i < 8; ++i)
    ob[i] = (short)f2b((v[i] - mean) * rstd * gg[i] + bb[i]);
  *(short8*)&outb[(size_t)row * DD + lane * 8] = ob;
}

// ---------------- logits = xc(bf16) @ Wout + bout,  N=25 --------------------
__global__ __launch_bounds__(256) void logits_k(const unsigned short* __restrict__ xb,
                                                const float* __restrict__ W,
                                                const float* __restrict__ bo,
                                                const int* __restrict__ Mptr,
                                                float* __restrict__ lg) {
  const int r0 = blockIdx.x * 8;
  if (r0 >= Mptr[0]) return;
  __shared__ float xs[8][516];
  for (int i = threadIdx.x; i < 512; i += 256) {
    const int rr = i >> 6, c8 = (i & 63) * 8;
    const short8 v = *(const short8*)&xb[(size_t)(r0 + rr) * DD + c8];
#pragma unroll
    for (int j = 0; j < 8; ++j) xs[rr][c8 + j] = b2f((unsigned short)v[j]);
  }
  __syncthreads();
  const int r = threadIdx.x >> 5, c = threadIdx.x & 31;
  if (c < CC) {
    float acc = 0.f;
#pragma unroll 8
    for (int k = 0; k < DD; ++k) acc += xs[r][k] * W[k * CC + c];
    lg[(size_t)(r0 + r) * CC + c] = acc + bo[c];
  }
}

// ---------------- CRF: linear-domain scan via v_readlane (compacted) --------
__global__ __launch_bounds__(64) void crf_k(const float* __restrict__ lg,
                                            const int* __restrict__ tag,
                                            const int* __restrict__ seq_len,
                                            const int* __restrict__ boff,
                                            const float* __restrict__ trans,
                                            float* __restrict__ nll) {
  __shared__ float eexp[TT * CC + 64];
  __shared__ float tr[CC * CC];
  const int b = blockIdx.x;
  const int l = threadIdx.x;
  const int len = seq_len[b];
  const float* lgb = lg + (size_t)boff[b] * CC;
  for (int i = l; i < len * CC; i += 64) eexp[i] = __expf(lgb[i]);
  for (int i = l; i < CC * CC; i += 64) tr[i] = trans[i];
  __syncthreads();
  const int lc = (l < CC) ? l : (CC - 1);
  float et[CC];
#pragma unroll
  for (int i = 0; i < CC; ++i) et[i] = __expf(tr[i * CC + lc]);
  const float e00 = lgb[0];
  float M = e00;
  float A = (l < CC) ? __expf(lgb[l] - e00) : 0.f;
  for (int t = 1; t < len; ++t) {
    const float e = eexp[t * CC + lc];
    float s0 = 0.f, s1 = 0.f, s2 = 0.f, s3 = 0.f, s4 = 0.f;
#pragma unroll
    for (int i = 0; i < CC; i += 5) {
      s0 += rdlane(A, i + 0) * et[i + 0];
      s1 += rdlane(A, i + 1) * et[i + 1];
      s2 += rdlane(A, i + 2) * et[i + 2];
      s3 += rdlane(A, i + 3) * et[i + 3];
      s4 += rdlane(A, i + 4) * et[i + 4];
    }
    A = (((s0 + s1) + (s2 + s3)) + s4) * e;
    if ((t & 3) == 0) {
      const float r = rdlane(A, 0);  // A_0 > 0 always (dense transitions)
      M += __logf(r);
      A *= __builtin_amdgcn_rcpf(r);
    }
  }
  const float tot = wredsum((l < CC) ? A : 0.f);
  float gold = 0.f;
  for (int t = l; t < len; t += 64)
    gold += lgb[t * CC + tag[b * TT + t]];
  for (int t = 1 + l; t < len; t += 64)
    gold += tr[tag[b * TT + t - 1] * CC + tag[b * TT + t]];
  gold = wredsum(gold);
  if (l == 0) nll[b] = (M + __logf(tot)) - gold;
}

__global__ __launch_bounds__(64) void final_k(const float* __restrict__ nll,
                                              float* __restrict__ out) {
  float v = nll[threadIdx.x];
  v = wredsum(v);
  if (threadIdx.x == 0) out[0] = v * (1.0f / 64.0f);
}

}  // namespace

extern "C" void kernel_launch(void* const* d_in, const int* in_sizes, int n_in,
                              void* d_out, int out_size, void* d_ws, size_t ws_size,
                              hipStream_t stream) {
  (void)in_sizes; (void)n_in; (void)out_size; (void)ws_size;
  const int* chi = (const int*)d_in[0];
  const int* wdi = (const int*)d_in[1];
  const int* psi = (const int*)d_in[2];
  const float* spo = (const float*)d_in[3];
  const int* seq_len = (const int*)d_in[4];
  const int* tag = (const int*)d_in[5];
  const float* ctab = (const float*)d_in[6];
  const float* wtab = (const float*)d_in[7];
  const float* ptab = (const float*)d_in[8];
  const float* ln0g = (const float*)d_in[9];
  const float* ln0b = (const float*)d_in[10];
  const float* Wq = (const float*)d_in[11];
  const float* bq = (const float*)d_in[12];
  const float* Wk = (const float*)d_in[13];
  const float* bk = (const float*)d_in[14];
  const float* Wv = (const float*)d_in[15];
  const float* bv = (const float*)d_in[16];
  const float* Wo = (const float*)d_in[17];
  const float* bo = (const float*)d_in[18];
  const float* ln1g = (const float*)d_in[19];
  const float* ln1b = (const float*)d_in[20];
  const float* W1 = (const float*)d_in[21];
  const float* b1 = (const float*)d_in[22];
  const float* W2 = (const float*)d_in[23];
  const float* b2 = (const float*)d_in[24];
  const float* ln2g = (const float*)d_in[25];
  const float* ln2b = (const float*)d_in[26];
  const float* Wout = (const float*)d_in[27];
  const float* bout = (const float*)d_in[28];
  const float* trans = (const float*)d_in[29];

  // ---- workspace layout (~221 MB), all buffers disjoint ----
  char* w8 = (char*)d_ws;
  unsigned short* ib  = (unsigned short*)(w8);             // 64MB ffn inner [16384][2048]
  unsigned short* xc  = (unsigned short*)(w8 + 64 * MB);   // 16MB x compact bf16
  unsigned short* cbx = (unsigned short*)(w8 + 80 * MB);   // 16MB ctx compact bf16
  unsigned short* ab  = (unsigned short*)(w8 + 96 * MB);   // 16MB att_out+x bf16
  unsigned short* hb  = (unsigned short*)(w8 + 112 * MB);  // 16MB h1 bf16
  unsigned short* t0b = (unsigned short*)(w8 + 128 * MB);  // 16MB ffn_out+h1 bf16
  unsigned short* qbuf = (unsigned short*)(w8 + 144 * MB); // 16MB q bf16 [B,H,T,DH]
  unsigned short* kbuf = (unsigned short*)(w8 + 160 * MB); // 16MB k bf16 [B,H,T,DH]
  _Float16* vtb = (_Float16*)(w8 + 176 * MB);              // 16MB v^T f16 [B,H,DH,T]
  unsigned short* wqkv = (unsigned short*)(w8 + 192 * MB); // [L][1536][512] 6MB
  unsigned short* wot = (unsigned short*)(w8 + 198 * MB);  // [L][512][512] 2MB
  unsigned short* w1t = (unsigned short*)(w8 + 200 * MB);  // [L][2048][512] 8MB
  unsigned short* w2t = (unsigned short*)(w8 + 208 * MB);  // [L][512][2048] 8MB
  float* lg = (float*)(w8 + 216 * MB);                     // 16384*25 f32
  float* nll = (float*)(w8 + 218 * MB);
  int* boff = (int*)(w8 + 219 * MB);                       // [65]; boff[64] = M'
  int* rowmap = (int*)(w8 + 220 * MB);                     // [16384] (b<<8)|t
  const int* Mptr = boff + 64;

  prefix_k<<<1, 64, 0, stream>>>(seq_len, boff);
  rowmap_k<<<BB, 256, 0, stream>>>(seq_len, boff, rowmap);

  const size_t QKVS = (size_t)1536 * 512;
  wconv_k<<<dim3(8, 8, LT), 256, 0, stream>>>(Wq, wqkv, DD, DD, QKVS);
  wconv_k<<<dim3(8, 8, LT), 256, 0, stream>>>(Wk, wqkv + 512 * 512, DD, DD, QKVS);
  wconv_k<<<dim3(8, 8, LT), 256, 0, stream>>>(Wv, wqkv + 1024 * 512, DD, DD, QKVS);
  wconv_k<<<dim3(8, 8, LT), 256, 0, stream>>>(Wo, wot, DD, DD, (size_t)DD * DD);
  wconv_k<<<dim3(8, 32, LT), 256, 0, stream>>>(W1, w1t, DD, FF, (size_t)DD * FF);
  wconv_k<<<dim3(32, 8, LT), 256, 0, stream>>>(W2, w2t, FF, DD, (size_t)FF * DD);

  embed_ln0_k<<<M_ALL, 64, 0, stream>>>(chi, wdi, psi, spo, ctab, wtab, ptab,
                                        ln0g, ln0b, seq_len, boff, xc);

  for (int l = 0; l < LT; ++l) {
    gemm_mfma<5><<<dim3(12, 128), 256, 0, stream>>>(
        xc, wqkv + (size_t)l * QKVS, bq + l * DD, bk + l * DD, bv + l * DD,
        nullptr, Mptr, rowmap, qbuf, kbuf, vtb, M_ALL, 1536, DD);
    attn_mfma_k<<<BB * HH, 256, 0, stream>>>(qbuf, kbuf, vtb, seq_len, boff, cbx);
    gemm_mfma<7><<<dim3(4, 128), 256, 0, stream>>>(
        cbx, wot + (size_t)l * DD * DD, bo + l * DD, nullptr, nullptr,
        xc, Mptr, nullptr, ab, nullptr, nullptr, M_ALL, DD, DD);
    ln_k<<<M_ALL, 64, 0, stream>>>(ab, ln1g + l * DD, ln1b + l * DD, Mptr, hb);
    gemm_mfma<1><<<dim3(FF / 128, 128), 256, 0, stream>>>(
        hb, w1t + (size_t)l * FF * DD, b1 + l * FF, nullptr, nullptr,
        nullptr, Mptr, nullptr, ib, nullptr, nullptr, M_ALL, FF, DD);
    gemm_mfma<7><<<dim3(DD / 128, 128), 256, 0, stream>>>(
        ib, w2t + (size_t)l * FF * DD, b2 + l * DD, nullptr, nullptr,
        hb, Mptr, nullptr, t0b, nullptr, nullptr, M_ALL, DD, FF);
    ln_k<<<M_ALL, 64, 0, stream>>>(t0b, ln2g + l * DD, ln2b + l * DD, Mptr, xc);
  }
  logits_k<<<M_ALL / 8, 256, 0, stream>>>(xc, Wout, bout, Mptr, lg);
  crf_k<<<BB, 64, 0, stream>>>(lg, tag, seq_len, boff, trans, nll);
  final_k<<<1, 64, 0, stream>>>(nll, (float*)d_out);
}

// Round 7
// 814.823 us; speedup vs baseline: 10.1100x; 1.0079x over previous
//
#include <hip/hip_runtime.h>
#include <cmath>

namespace {

constexpr int LT = 4;       // layers
constexpr int BB = 64;      // batch
constexpr int TT = 256;     // seq len
constexpr int DD = 512;     // model dim
constexpr int HH = 8;       // heads
constexpr int DH = 64;      // head dim
constexpr int FF = 2048;    // ffn inner
constexpr int CC = 25;      // tag classes
constexpr int M_ALL = BB * TT;   // 16384 padded token rows
constexpr size_t MB = 1024 * 1024;

typedef __attribute__((ext_vector_type(8))) short short8;
typedef __attribute__((ext_vector_type(4))) short short4_;
typedef __attribute__((ext_vector_type(4))) float f32x4;
typedef __attribute__((ext_vector_type(4))) _Float16 half4;

__device__ __forceinline__ float b2f(unsigned short u) {
  union { unsigned int i; float f; } x; x.i = ((unsigned int)u) << 16; return x.f;
}
__device__ __forceinline__ unsigned short f2b(float f) {
  union { float f; unsigned int i; } x; x.f = f;
  unsigned int r = x.i + 0x7FFFu + ((x.i >> 16) & 1u);
  return (unsigned short)(r >> 16);
}
__device__ __forceinline__ float rdlane(float v, int l) {
  union { float f; unsigned int i; } x; x.f = v;
  x.i = (unsigned int)__builtin_amdgcn_readlane((int)x.i, l);
  return x.f;
}
__device__ __forceinline__ void gl_lds16(const void* g, void* l) {
  __builtin_amdgcn_global_load_lds(
      (const __attribute__((address_space(1))) unsigned int*)g,
      (__attribute__((address_space(3))) unsigned int*)l, 16, 0, 0);
}
__device__ __forceinline__ float wredsum(float v) {
#pragma unroll
  for (int o = 32; o > 0; o >>= 1) v += __shfl_xor(v, o, 64);
  return v;
}

// ---------------- token compaction: boff prefix + rowmap --------------------
__global__ __launch_bounds__(64) void prefix_k(const int* __restrict__ sl,
                                               int* __restrict__ boff) {
  const int l = threadIdx.x;
  int s = sl[l];
#pragma unroll
  for (int o = 1; o < 64; o <<= 1) {
    const int u = __shfl_up(s, o, 64);
    if (l >= o) s += u;
  }
  boff[l + 1] = s;          // boff[64] == M' (valid row count)
  if (l == 0) boff[0] = 0;
}

__global__ __launch_bounds__(256) void rowmap_k(const int* __restrict__ sl,
                                                const int* __restrict__ boff,
                                                int* __restrict__ rowmap) {
  const int b = blockIdx.x, t = threadIdx.x;
  if (t < sl[b]) rowmap[boff[b] + t] = (b << 8) | t;
}

// ---------------- weight convert+transpose: [K,N] f32 -> [N,K] bf16 ---------
__global__ __launch_bounds__(256) void wconv_k(const float* __restrict__ in,
                                               unsigned short* __restrict__ out,
                                               int K, int N, size_t lstride) {
  __shared__ float ts[64][65];
  const int k0 = blockIdx.x * 64, n0 = blockIdx.y * 64;
  in += (size_t)blockIdx.z * K * N;
  out += (size_t)blockIdx.z * lstride;
  const int tid = threadIdx.x;
  for (int i = tid; i < 1024; i += 256) {
    const int r = i >> 4, c4 = i & 15;
    const float4 f = *(const float4*)&in[(size_t)(k0 + r) * N + n0 + c4 * 4];
    ts[r][c4 * 4 + 0] = f.x; ts[r][c4 * 4 + 1] = f.y;
    ts[r][c4 * 4 + 2] = f.z; ts[r][c4 * 4 + 3] = f.w;
  }
  __syncthreads();
  const int n_r = tid >> 2, kc = (tid & 3) * 16;
  short8 v0, v1;
#pragma unroll
  for (int j = 0; j < 8; ++j) {
    v0[j] = (short)f2b(ts[kc + j][n_r]);
    v1[j] = (short)f2b(ts[kc + 8 + j][n_r]);
  }
  unsigned short* op = out + (size_t)(n0 + n_r) * K + k0 + kc;
  *(short8*)op = v0;
  *(short8*)(op + 8) = v1;
}

// ---------------- embed + LN0 -> compacted bf16 (4 rows / block) ------------
__global__ __launch_bounds__(256) void embed_ln0_k(
    const int* __restrict__ ch, const int* __restrict__ wd, const int* __restrict__ ps,
    const float* __restrict__ spo, const float* __restrict__ ctab,
    const float* __restrict__ wtab, const float* __restrict__ ptab,
    const float* __restrict__ g, const float* __restrict__ be,
    const int* __restrict__ sl, const int* __restrict__ boff,
    unsigned short* __restrict__ xc) {
  const int row = blockIdx.x * 4 + (threadIdx.x >> 6);
  const int b = row >> 8, t = row & 255;
  if (t >= sl[b]) return;            // dead token (per-wave uniform exit)
  const int orow = boff[b] + t;
  const int lane = threadIdx.x & 63;
  const int ci = ch[row], wi = wd[row], pi = ps[row];
  float v[8];
#pragma unroll
  for (int j = 0; j < 2; ++j) {
    const int d = j * 256 + lane * 4;
    float4 f;
    if (d < 128)      f = *(const float4*)&ctab[(size_t)ci * 128 + d];
    else if (d < 428) f = *(const float4*)&wtab[(size_t)wi * 300 + (d - 128)];
    else if (d < 492) f = *(const float4*)&ptab[(size_t)pi * 64 + (d - 428)];
    else              f = *(const float4*)&spo[(size_t)b * 20 + (d - 492)];
    v[j * 4 + 0] = f.x; v[j * 4 + 1] = f.y; v[j * 4 + 2] = f.z; v[j * 4 + 3] = f.w;
  }
  float s = 0.f;
#pragma unroll
  for (int i = 0; i < 8; ++i) s += v[i];
  const float mean = wredsum(s) * (1.0f / 512.0f);
  float vs = 0.f;
#pragma unroll
  for (int i = 0; i < 8; ++i) { const float d = v[i] - mean; vs += d * d; }
  const float rstd = rsqrtf(wredsum(vs) * (1.0f / 512.0f) + 1e-5f);
#pragma unroll
  for (int j = 0; j < 2; ++j) {
    const int d = j * 256 + lane * 4;
    const float4 gv = *(const float4*)&g[d];
    const float4 bv = *(const float4*)&be[d];
    short4_ ob;
    ob[0] = (short)f2b((v[j * 4 + 0] - mean) * rstd * gv.x + bv.x);
    ob[1] = (short)f2b((v[j * 4 + 1] - mean) * rstd * gv.y + bv.y);
    ob[2] = (short)f2b((v[j * 4 + 2] - mean) * rstd * gv.z + bv.z);
    ob[3] = (short)f2b((v[j * 4 + 3] - mean) * rstd * gv.w + bv.w);
    *(short4_*)&xc[(size_t)orow * DD + d] = ob;
  }
}

// ---------------- MFMA GEMM, 2-phase double-buffered (T3-min) ---------------
// EPI: 1 bf16+bias+relu; 5 fused QKV scatter via rowmap; 7 bf16+bias+bf16 res
template <int EPI>
__global__ __launch_bounds__(256) void gemm_mfma(
    const unsigned short* __restrict__ A, const unsigned short* __restrict__ Bt,
    const float* __restrict__ bias, const float* __restrict__ bias2,
    const float* __restrict__ bias3, const unsigned short* __restrict__ res,
    const int* __restrict__ Mptr, const int* __restrict__ rowmap,
    void* __restrict__ outv, void* __restrict__ out2v, void* __restrict__ out3v,
    int M, int N, int K) {
  const int Mp = Mptr[0];
  const int m0 = blockIdx.y * 128, n0 = blockIdx.x * 128;
  if (m0 >= Mp) return;  // block-uniform exit (whole tile dead)
  __shared__ unsigned short As[2][128 * 64];
  __shared__ unsigned short Bs[2][128 * 64];
  const int tid = threadIdx.x;
  const int wid = tid >> 6, lane = tid & 63;
  const int wr = wid >> 1, wc = wid & 1;
  const int cl = lane & 15, rg = lane >> 4;
  f32x4 acc[4][4];
#pragma unroll
  for (int i = 0; i < 4; ++i)
#pragma unroll
    for (int j = 0; j < 4; ++j) acc[i][j] = (f32x4){0.f, 0.f, 0.f, 0.f};

  const int rbase = tid >> 3, sl = tid & 7;
  const int sc = 8 * (sl ^ (rbase & 7));  // pre-swizzled source column (elems)

  auto stage = [&](int buf, int k0) {
#pragma unroll
    for (int i = 0; i < 4; ++i) {
      const int r = i * 32 + rbase;
      gl_lds16(A + (size_t)(m0 + r) * K + k0 + sc,
               (char*)As[buf] + (i * 256 + tid) * 16);
      gl_lds16(Bt + (size_t)(n0 + r) * K + k0 + sc,
               (char*)Bs[buf] + (i * 256 + tid) * 16);
    }
  };

  stage(0, 0);
  __syncthreads();  // implicit vmcnt(0) drain: buf0 staged
  int cur = 0;
  for (int k0 = 0; k0 < K; k0 += 64) {
    if (k0 + 64 < K) stage(cur ^ 1, k0 + 64);  // issue-ahead: hides under MFMA
#pragma unroll
    for (int ks = 0; ks < 2; ++ks) {
      short8 a[4], b[4];
      const int kbyte = ks * 64 + rg * 16;
#pragma unroll
      for (int f = 0; f < 4; ++f) {
        const int am = wr * 64 + f * 16 + cl;
        a[f] = *(const short8*)((const char*)As[cur] + am * 128 +
                                (kbyte ^ ((am & 7) << 4)));
        const int bn = wc * 64 + f * 16 + cl;
        b[f] = *(const short8*)((const char*)Bs[cur] + bn * 128 +
                                (kbyte ^ ((bn & 7) << 4)));
      }
#pragma unroll
      for (int mi = 0; mi < 4; ++mi)
#pragma unroll
        for (int ni = 0; ni < 4; ++ni)
          acc[mi][ni] = __builtin_amdgcn_mfma_f32_16x16x32_bf16(a[mi], b[ni],
                                                                acc[mi][ni], 0, 0, 0);
    }
    __syncthreads();  // drains this iter's stage; frees buf[cur] for next stage
    cur ^= 1;
  }

  int rm[4][4];
  if constexpr (EPI == 5) {
#pragma unroll
    for (int mi = 0; mi < 4; ++mi) {
      const int mb_ = m0 + wr * 64 + mi * 16 + rg * 4;
#pragma unroll
      for (int i = 0; i < 4; ++i)
        rm[mi][i] = (mb_ + i < Mp) ? rowmap[mb_ + i] : -1;
    }
  }

#pragma unroll
  for (int ni = 0; ni < 4; ++ni) {
    const int n = n0 + wc * 64 + ni * 16 + cl;
    float bv;
    if constexpr (EPI == 5) {
      bv = (n < 512) ? bias[n] : (n < 1024 ? bias2[n - 512] : bias3[n - 1024]);
    } else {
      bv = bias[n];
    }
#pragma unroll
    for (int mi = 0; mi < 4; ++mi) {
      if constexpr (EPI == 5) {
        const int hh = (n >> 6) & 7, d = n & 63;
        if (n < 1024) {        // q or k scatter [B,H,T,DH] bf16
          unsigned short* outp = (unsigned short*)((n < 512) ? outv : out2v);
#pragma unroll
          for (int i = 0; i < 4; ++i) {
            const int rmv = rm[mi][i];
            if (rmv >= 0) {
              const int bb = rmv >> 8, tt = rmv & 255;
              outp[(((size_t)(bb * HH + hh) * TT + tt) << 6) + d] =
                  f2b(acc[mi][ni][i] + bv);
            }
          }
        } else {               // v scatter [B,H,DH,T] f16
          const int rm0 = rm[mi][0];
          if (rm0 >= 0 && rm[mi][3] == rm0 + 3) {   // contiguous, same b
            half4 pk;
#pragma unroll
            for (int i = 0; i < 4; ++i) pk[i] = (_Float16)(acc[mi][ni][i] + bv);
            *(half4*)((_Float16*)out3v +
                      ((((size_t)((rm0 >> 8) * HH + hh) * DH + d) << 8) + (rm0 & 255))) = pk;
          } else {
#pragma unroll
            for (int i = 0; i < 4; ++i) {
              const int rmv = rm[mi][i];
              if (rmv >= 0)
                ((_Float16*)out3v)[(((size_t)((rmv >> 8) * HH + hh) * DH + d) << 8) +
                                   (rmv & 255)] = (_Float16)(acc[mi][ni][i] + bv);
            }
          }
        }
      } else {
#pragma unroll
        for (int i = 0; i < 4; ++i) {
          const int m = m0 + wr * 64 + mi * 16 + rg * 4 + i;
          const float v = acc[mi][ni][i] + bv;
          if constexpr (EPI == 1) {
            ((unsigned short*)outv)[(size_t)m * N + n] = f2b(fmaxf(v, 0.f));
          } else if constexpr (EPI == 7) {
            ((unsigned short*)outv)[(size_t)m * N + n] =
                f2b(v + b2f(res[(size_t)m * N + n]));
          }
        }
      }
    }
  }
}

// ---------------- MFMA flash attention (compacted ctx out) ------------------
__global__ __launch_bounds__(256) void attn_mfma_k(
    const unsigned short* __restrict__ qb, const unsigned short* __restrict__ kbp,
    const _Float16* __restrict__ vtp, const int* __restrict__ seq_len,
    const int* __restrict__ boff, unsigned short* __restrict__ cb) {
  __shared__ unsigned short Ks[256 * 64];  // [t][d] bf16, 16B-slot XOR swizzle
  __shared__ _Float16 Vs[64 * 256];        // [d][t] f16, swizzled
  __shared__ unsigned short Os[64 * 64];   // out transpose stage, swizzled
  const int bh = blockIdx.x;
  const int b = bh >> 3, h = bh & 7;
  const int tid = threadIdx.x;
  const int wid = tid >> 6, lane = tid & 63;
  const int cl = lane & 15, rg = lane >> 4;
  const int len = seq_len[b];
  const int off = boff[b];

  {  // stage K (len-bounded) and full V^T
    const int r = tid >> 3, sl = tid & 7;
#pragma unroll
    for (int i = 0; i < 8; ++i) {
      if (i * 32 < len) {   // block-uniform skip of dead K rows
        const int row = i * 32 + r;
        gl_lds16(kbp + ((size_t)bh * TT + row) * DH + 8 * (sl ^ (row & 7)),
                 (char*)Ks + (i * 256 + tid) * 16);
      }
    }
#pragma unroll
    for (int i = 0; i < 8; ++i) {
      const int u = i * 256 + tid;
      const int vrow = u >> 5, vsl = u & 31;
      gl_lds16(vtp + ((size_t)bh * DH + vrow) * TT + 8 * (vsl ^ (vrow & 7)),
               (char*)Vs + u * 16);
    }
  }
  __syncthreads();

  for (int qt4 = 0; qt4 < 4; ++qt4) {
    if (qt4 * 64 >= len) break;  // block-uniform
    f32x4 o[4];
#pragma unroll
    for (int db = 0; db < 4; ++db) o[db] = (f32x4){0.f, 0.f, 0.f, 0.f};
    {
      const int q0 = qt4 * 64 + wid * 16;
      short8 bqf[2];
      const unsigned short* qp = qb + ((size_t)bh * TT + q0 + cl) * DH + rg * 8;
      bqf[0] = *(const short8*)qp;
      bqf[1] = *(const short8*)(qp + 32);
      f32x4 s[16];
#pragma unroll
      for (int kk = 0; kk < 16; ++kk) {
        s[kk] = (f32x4){0.f, 0.f, 0.f, 0.f};
        if (kk * 16 < len) {
          const int row = kk * 16 + cl;
          const char* base = (const char*)Ks + row * 128;
          const int sw = (row & 7) << 4;
          const short8 a0 = *(const short8*)(base + ((rg * 16) ^ sw));
          const short8 a1 = *(const short8*)(base + ((64 + rg * 16) ^ sw));
          s[kk] = __builtin_amdgcn_mfma_f32_16x16x32_bf16(a0, bqf[0], s[kk], 0, 0, 0);
          s[kk] = __builtin_amdgcn_mfma_f32_16x16x32_bf16(a1, bqf[1], s[kk], 0, 0, 0);
        }
      }
      float mx = -3.0e38f;
#pragma unroll
      for (int kk = 0; kk < 16; ++kk)
        if (kk * 16 < len) {
#pragma unroll
          for (int i = 0; i < 4; ++i) {
            float v = s[kk][i] * 0.125f;
            v = (kk * 16 + rg * 4 + i < len) ? v : -3.0e38f;
            s[kk][i] = v;
            mx = fmaxf(mx, v);
          }
        }
      mx = fmaxf(mx, __shfl_xor(mx, 16, 64));
      mx = fmaxf(mx, __shfl_xor(mx, 32, 64));
      float lsum = 0.f;
#pragma unroll
      for (int kk = 0; kk < 16; ++kk)
        if (kk * 16 < len) {
#pragma unroll
          for (int i = 0; i < 4; ++i) {
            const float p = __expf(s[kk][i] - mx);
            s[kk][i] = p;
            lsum += p;
          }
        }
      lsum += __shfl_xor(lsum, 16, 64);
      lsum += __shfl_xor(lsum, 32, 64);
      const float rl = 1.0f / lsum;
#pragma unroll
      for (int kk = 0; kk < 16; ++kk)
        if (kk * 16 < len) {
          half4 bp;
#pragma unroll
          for (int i = 0; i < 4; ++i) bp[i] = (_Float16)(s[kk][i] * rl);
#pragma unroll
          for (int db = 0; db < 4; ++db) {
            const int vrow = db * 16 + cl;
            const int byte = kk * 32 + rg * 8;
            const half4 a = *(const half4*)((const char*)Vs + vrow * 512 +
                              ((byte & ~15) ^ ((vrow & 7) << 4)) + (byte & 15));
            o[db] = __builtin_amdgcn_mfma_f32_16x16x16f16(a, bp, o[db], 0, 0, 0);
          }
        }
    }
    __syncthreads();
    {
      const int orow = wid * 16 + cl;
      char* obase = (char*)Os + orow * 128;
      const int sw = (orow & 7) << 4;
#pragma unroll
      for (int db = 0; db < 4; ++db) {
        short4_ pk;
#pragma unroll
        for (int i = 0; i < 4; ++i) pk[i] = (short)f2b(o[db][i]);
        const int byte = db * 32 + rg * 8;
        *(short4_*)(obase + ((byte & ~15) ^ sw) + (byte & 15)) = pk;
      }
    }
    __syncthreads();
    {  // coalesced copy Os -> compacted cb, rows t < len only
      const int r = tid >> 2, part = tid & 3;
      const int t = qt4 * 64 + r;
      if (t < len) {
        const int sw = (r & 7) << 4;
        const char* rbase = (const char*)Os + r * 128;
        const short8 w0 = *(const short8*)(rbase + ((part * 32) ^ sw));
        const short8 w1 = *(const short8*)(rbase + ((part * 32 + 16) ^ sw));
        unsigned short* dst = cb + ((size_t)(off + t)) * DD + h * DH + part * 16;
        *(short8*)dst = w0;
        *(short8*)(dst + 8) = w1;
      }
    }
  }
}

// ---------------- row LayerNorm (compacted, 4 rows / block) -----------------
__global__ __launch_bounds__(256) void ln_k(const unsigned short* __restrict__ a,
                                            const float* __restrict__ g,
                                            const float* __restrict__ be,
                                            const int* __restrict__ Mptr,
                                            unsigned short* __restrict__ outb) {
  const int row = blockIdx.x * 4 + (threadIdx.x >> 6);
  if (row >= Mptr[0]) return;  // per-wave uniform exit (no barriers below)
  const int lane = threadIdx.x & 63;
  float v[8];
  {
    const short8 va = *(const short8*)&a[(size_t)row * DD + lane * 8];
#pragma unroll
    for (int i = 0; i < 8; ++i) v[i] = b2f((unsigned short)va[i]);
  }
  float s = 0.f;
#pragma unroll
  for (int i = 0; i < 8; ++i) s += v[i];
  const float mean = wredsum(s) * (1.0f / 512.0f);
  float vs = 0.f;
#pragma unroll
  for (int i = 0; i < 8; ++i) { const float d = v[i] - mean; vs += d * d; }
  const float rstd = rsqrtf(wredsum(vs) * (1.0f / 512.0f) + 1e-5f);
  const float4 g0 = *(const float4*)&g[lane * 8];
  const float4 g1 = *(const float4*)&g[lane * 8 + 4];
  const float4 b0 = *(const float4*)&be[lane * 8];
  const float4 b1 = *(const float4*)&be[lane * 8 + 4];
  const float gg[8] = {g0.x, g0.y, g0.z, g0.w, g1.x, g1.y, g1.z, g1.w};
  const float bb[8] = {b0.x, b0.y, b0.z, b0.w, b1.x, b1.y, b1.z, b1.w};
  short8 ob;
#pragma unroll
  for (int i = 0; i < 8; ++i)
    ob[i] = (short)f2b((v[i] - mean) * rstd * gg[i] + bb[i]);
  *(short8*)&outb[(size_t)row * DD + lane * 8] = ob;
}

// ---------------- logits = xc(bf16) @ Wout + bout,  N=25 --------------------
__global__ __launch_bounds__(256) void logits_k(const unsigned short* __restrict__ xb,
                                                const float* __restrict__ W,
                                                const float* __restrict__ bo,
                                                const int* __restrict__ Mptr,
                                                float* __restrict__ lg) {
  const int r0 = blockIdx.x * 8;
  if (r0 >= Mptr[0]) return;
  __shared__ float xs[8][516];
  for (int i = threadIdx.x; i < 512; i += 256) {
    const int rr = i >> 6, c8 = (i & 63) * 8;
    const short8 v = *(const short8*)&xb[(size_t)(r0 + rr) * DD + c8];
#pragma unroll
    for (int j = 0; j < 8; ++j) xs[rr][c8 + j] = b2f((unsigned short)v[j]);
  }
  __syncthreads();
  const int r = threadIdx.x >> 5, c = threadIdx.x & 31;
  if (c < CC) {
    float acc = 0.f;
#pragma unroll 8
    for (int k = 0; k < DD; ++k) acc += xs[r][k] * W[k * CC + c];
    lg[(size_t)(r0 + r) * CC + c] = acc + bo[c];
  }
}

// ---------------- CRF: linear-domain scan via v_readlane (compacted) --------
__global__ __launch_bounds__(64) void crf_k(const float* __restrict__ lg,
                                            const int* __restrict__ tag,
                                            const int* __restrict__ seq_len,
                                            const int* __restrict__ boff,
                                            const float* __restrict__ trans,
                                            float* __restrict__ nll) {
  __shared__ float eexp[TT * CC + 64];
  __shared__ float tr[CC * CC];
  const int b = blockIdx.x;
  const int l = threadIdx.x;
  const int len = seq_len[b];
  const float* lgb = lg + (size_t)boff[b] * CC;
  for (int i = l; i < len * CC; i += 64) eexp[i] = __expf(lgb[i]);
  for (int i = l; i < CC * CC; i += 64) tr[i] = trans[i];
  __syncthreads();
  const int lc = (l < CC) ? l : (CC - 1);
  float et[CC];
#pragma unroll
  for (int i = 0; i < CC; ++i) et[i] = __expf(tr[i * CC + lc]);
  const float e00 = lgb[0];
  float M = e00;
  float A = (l < CC) ? __expf(lgb[l] - e00) : 0.f;
  for (int t = 1; t < len; ++t) {
    const float e = eexp[t * CC + lc];
    float s0 = 0.f, s1 = 0.f, s2 = 0.f, s3 = 0.f, s4 = 0.f;
#pragma unroll
    for (int i = 0; i < CC; i += 5) {
      s0 += rdlane(A, i + 0) * et[i + 0];
      s1 += rdlane(A, i + 1) * et[i + 1];
      s2 += rdlane(A, i + 2) * et[i + 2];
      s3 += rdlane(A, i + 3) * et[i + 3];
      s4 += rdlane(A, i + 4) * et[i + 4];
    }
    A = (((s0 + s1) + (s2 + s3)) + s4) * e;
    if ((t & 3) == 0) {
      const float r = rdlane(A, 0);  // A_0 > 0 always (dense transitions)
      M += __logf(r);
      A *= __builtin_amdgcn_rcpf(r);
    }
  }
  const float tot = wredsum((l < CC) ? A : 0.f);
  float gold = 0.f;
  for (int t = l; t < len; t += 64)
    gold += lgb[t * CC + tag[b * TT + t]];
  for (int t = 1 + l; t < len; t += 64)
    gold += tr[tag[b * TT + t - 1] * CC + tag[b * TT + t]];
  gold = wredsum(gold);
  if (l == 0) nll[b] = (M + __logf(tot)) - gold;
}

__global__ __launch_bounds__(64) void final_k(const float* __restrict__ nll,
                                              float* __restrict__ out) {
  float v = nll[threadIdx.x];
  v = wredsum(v);
  if (threadIdx.x == 0) out[0] = v * (1.0f / 64.0f);
}

}  // namespace

extern "C" void kernel_launch(void* const* d_in, const int* in_sizes, int n_in,
                              void* d_out, int out_size, void* d_ws, size_t ws_size,
                              hipStream_t stream) {
  (void)in_sizes; (void)n_in; (void)out_size; (void)ws_size;
  const int* chi = (const int*)d_in[0];
  const int* wdi = (const int*)d_in[1];
  const int* psi = (const int*)d_in[2];
  const float* spo = (const float*)d_in[3];
  const int* seq_len = (const int*)d_in[4];
  const int* tag = (const int*)d_in[5];
  const float* ctab = (const float*)d_in[6];
  const float* wtab = (const float*)d_in[7];
  const float* ptab = (const float*)d_in[8];
  const float* ln0g = (const float*)d_in[9];
  const float* ln0b = (const float*)d_in[10];
  const float* Wq = (const float*)d_in[11];
  const float* bq = (const float*)d_in[12];
  const float* Wk = (const float*)d_in[13];
  const float* bk = (const float*)d_in[14];
  const float* Wv = (const float*)d_in[15];
  const float* bv = (const float*)d_in[16];
  const float* Wo = (const float*)d_in[17];
  const float* bo = (const float*)d_in[18];
  const float* ln1g = (const float*)d_in[19];
  const float* ln1b = (const float*)d_in[20];
  const float* W1 = (const float*)d_in[21];
  const float* b1 = (const float*)d_in[22];
  const float* W2 = (const float*)d_in[23];
  const float* b2 = (const float*)d_in[24];
  const float* ln2g = (const float*)d_in[25];
  const float* ln2b = (const float*)d_in[26];
  const float* Wout = (const float*)d_in[27];
  const float* bout = (const float*)d_in[28];
  const float* trans = (const float*)d_in[29];

  // ---- workspace layout (~221 MB), all buffers disjoint ----
  char* w8 = (char*)d_ws;
  unsigned short* ib  = (unsigned short*)(w8);             // 64MB ffn inner [16384][2048]
  unsigned short* xc  = (unsigned short*)(w8 + 64 * MB);   // 16MB x compact bf16
  unsigned short* cbx = (unsigned short*)(w8 + 80 * MB);   // 16MB ctx compact bf16
  unsigned short* ab  = (unsigned short*)(w8 + 96 * MB);   // 16MB att_out+x bf16
  unsigned short* hb  = (unsigned short*)(w8 + 112 * MB);  // 16MB h1 bf16
  unsigned short* t0b = (unsigned short*)(w8 + 128 * MB);  // 16MB ffn_out+h1 bf16
  unsigned short* qbuf = (unsigned short*)(w8 + 144 * MB); // 16MB q bf16 [B,H,T,DH]
  unsigned short* kbuf = (unsigned short*)(w8 + 160 * MB); // 16MB k bf16 [B,H,T,DH]
  _Float16* vtb = (_Float16*)(w8 + 176 * MB);              // 16MB v^T f16 [B,H,DH,T]
  unsigned short* wqkv = (unsigned short*)(w8 + 192 * MB); // [L][1536][512] 6MB
  unsigned short* wot = (unsigned short*)(w8 + 198 * MB);  // [L][512][512] 2MB
  unsigned short* w1t = (unsigned short*)(w8 + 200 * MB);  // [L][2048][512] 8MB
  unsigned short* w2t = (unsigned short*)(w8 + 208 * MB);  // [L][512][2048] 8MB
  float* lg = (float*)(w8 + 216 * MB);                     // 16384*25 f32
  float* nll = (float*)(w8 + 218 * MB);
  int* boff = (int*)(w8 + 219 * MB);                       // [65]; boff[64] = M'
  int* rowmap = (int*)(w8 + 220 * MB);                     // [16384] (b<<8)|t
  const int* Mptr = boff + 64;

  prefix_k<<<1, 64, 0, stream>>>(seq_len, boff);
  rowmap_k<<<BB, 256, 0, stream>>>(seq_len, boff, rowmap);

  const size_t QKVS = (size_t)1536 * 512;
  wconv_k<<<dim3(8, 8, LT), 256, 0, stream>>>(Wq, wqkv, DD, DD, QKVS);
  wconv_k<<<dim3(8, 8, LT), 256, 0, stream>>>(Wk, wqkv + 512 * 512, DD, DD, QKVS);
  wconv_k<<<dim3(8, 8, LT), 256, 0, stream>>>(Wv, wqkv + 1024 * 512, DD, DD, QKVS);
  wconv_k<<<dim3(8, 8, LT), 256, 0, stream>>>(Wo, wot, DD, DD, (size_t)DD * DD);
  wconv_k<<<dim3(8, 32, LT), 256, 0, stream>>>(W1, w1t, DD, FF, (size_t)DD * FF);
  wconv_k<<<dim3(32, 8, LT), 256, 0, stream>>>(W2, w2t, FF, DD, (size_t)FF * DD);

  embed_ln0_k<<<M_ALL / 4, 256, 0, stream>>>(chi, wdi, psi, spo, ctab, wtab, ptab,
                                             ln0g, ln0b, seq_len, boff, xc);

  for (int l = 0; l < LT; ++l) {
    gemm_mfma<5><<<dim3(12, 128), 256, 0, stream>>>(
        xc, wqkv + (size_t)l * QKVS, bq + l * DD, bk + l * DD, bv + l * DD,
        nullptr, Mptr, rowmap, qbuf, kbuf, vtb, M_ALL, 1536, DD);
    attn_mfma_k<<<BB * HH, 256, 0, stream>>>(qbuf, kbuf, vtb, seq_len, boff, cbx);
    gemm_mfma<7><<<dim3(4, 128), 256, 0, stream>>>(
        cbx, wot + (size_t)l * DD * DD, bo + l * DD, nullptr, nullptr,
        xc, Mptr, nullptr, ab, nullptr, nullptr, M_ALL, DD, DD);
    ln_k<<<M_ALL / 4, 256, 0, stream>>>(ab, ln1g + l * DD, ln1b + l * DD, Mptr, hb);
    gemm_mfma<1><<<dim3(FF / 128, 128), 256, 0, stream>>>(
        hb, w1t + (size_t)l * FF * DD, b1 + l * FF, nullptr, nullptr,
        nullptr, Mptr, nullptr, ib, nullptr, nullptr, M_ALL, FF, DD);
    gemm_mfma<7><<<dim3(DD / 128, 128), 256, 0, stream>>>(
        ib, w2t + (size_t)l * FF * DD, b2 + l * DD, nullptr, nullptr,
        hb, Mptr, nullptr, t0b, nullptr, nullptr, M_ALL, DD, FF);
    ln_k<<<M_ALL / 4, 256, 0, stream>>>(t0b, ln2g + l * DD, ln2b + l * DD, Mptr, xc);
  }
  logits_k<<<M_ALL / 8, 256, 0, stream>>>(xc, Wout, bout, Mptr, lg);
  crf_k<<<BB, 64, 0, stream>>>(lg, tag, seq_len, boff, trans, nll);
  final_k<<<1, 64, 0, stream>>>(nll, (float*)d_out);
}